// Round 8
// baseline (1300.826 us; speedup 1.0000x reference)
//
#include <hip/hip_runtime.h>

#define NN     50000
#define NRELB  20
#define RR     (2*NRELB + 1)      // 41
#define NHID   16
#define NCLASS 50
#define EB     1600000
#define WPB    4                  // waves per block (layer1)
#define NPB    8                  // nodes per block (agg) = waves per block
#define RH     (RR * NHID)        // 656
#define NPBRH  (NPB * RH)         // 5248
#define STRIDE 128                // static CSR bucket size (max deg ~65+8*sigma << 128)
#define KPAD   672                // 656 padded to 8*84
#define KU32   (KPAD/2)           // 336 u32 (bf16 pairs) per af row
#define KB     (KPAD/8)           // 84 k-blocks of 8
#define NROWS  50048              // 782*64 af rows (padded)

__device__ __forceinline__ unsigned bf16r(float x) {     // fp32 -> bf16 bits, RNE
    unsigned b = __float_as_uint(x);
    return (b + 0x7fffu + ((b >> 16) & 1u)) >> 16;
}

// Seed each node's bucket with its self-loop at slot 0.
__global__ void init_kernel(unsigned* __restrict__ cnt, unsigned* __restrict__ ekey) {
    int n = blockIdx.x * blockDim.x + threadIdx.x;
    if (n >= NN) return;
    cnt[n] = 1u;
    ekey[(size_t)n * STRIDE] = ((unsigned)(2 * NRELB) << 16) | (unsigned)n;
}

// One thread per base edge: emit forward + inverse into static buckets.
__global__ void scatter_kernel(const int* __restrict__ src, const int* __restrict__ rel,
                               const int* __restrict__ dst,
                               unsigned* __restrict__ cnt, unsigned* __restrict__ ekey) {
    int e = blockIdx.x * blockDim.x + threadIdx.x;
    if (e >= EB) return;
    int s = src[e], r = rel[e], o = dst[e];
    unsigned p1 = atomicAdd(&cnt[s], 1u);
    ekey[(size_t)s * STRIDE + p1] = ((unsigned)r << 16) | (unsigned)o;
    unsigned p2 = atomicAdd(&cnt[o], 1u);
    ekey[(size_t)o * STRIDE + p2] = ((unsigned)(r + NRELB) << 16) | (unsigned)s;
}

// Layer 1: one wave per node. Bucket keys staged in LDS; 4-deep branch-free
// gather pipeline; h-major LDS accumulator [h*41+r].
__global__ __launch_bounds__(256) void layer1_kernel(
        const unsigned* __restrict__ ekey, const unsigned* __restrict__ cnt,
        const float* __restrict__ W1, const float* __restrict__ b1,
        float* __restrict__ h) {
    __shared__ float acc[WPB][RH];      // [h*41 + r]
    __shared__ float degL[WPB][RR];
    __shared__ unsigned keyc[WPB][STRIDE];
    const int wave = threadIdx.x >> 6, lane = threadIdx.x & 63;
    const int n = blockIdx.x * WPB + wave;
    for (int i = lane; i < RH; i += 64) acc[wave][i] = 0.f;
    if (lane < RR) degL[wave][lane] = 0.f;
    // stage this node's full key bucket (wave-private; poison slots never read)
    {
        const unsigned* ek = ekey + (size_t)n * STRIDE;
        keyc[wave][lane]      = ek[lane];
        keyc[wave][64 + lane] = ek[64 + lane];
    }
    __syncthreads();
    if (n < NN) {
        const int deg = cnt[n];
        const int dm1 = deg - 1;
        const int g = lane >> 2, q = (lane & 3) * 4;
        const bool lead = (lane & 3) == 0;
        for (int i = 0; i < deg; i += 64) {
            const int i0 = i + g;
            const int j0 = min(i0,      dm1), j1 = min(i0 + 16, dm1);
            const int j2 = min(i0 + 32, dm1), j3 = min(i0 + 48, dm1);
            const unsigned k0 = keyc[wave][j0], k1 = keyc[wave][j1];
            const unsigned k2 = keyc[wave][j2], k3 = keyc[wave][j3];
            const float m0 = (i0      < deg) ? 1.f : 0.f;
            const float m1 = (i0 + 16 < deg) ? 1.f : 0.f;
            const float m2 = (i0 + 32 < deg) ? 1.f : 0.f;
            const float m3 = (i0 + 48 < deg) ? 1.f : 0.f;
            const int r0 = k0 >> 16, r1 = k1 >> 16, r2 = k2 >> 16, r3 = k3 >> 16;
            float4 v0 = *(const float4*)(W1 + ((size_t)(r0 * NN + (k0 & 0xFFFF))) * NHID + q);
            float4 v1 = *(const float4*)(W1 + ((size_t)(r1 * NN + (k1 & 0xFFFF))) * NHID + q);
            float4 v2 = *(const float4*)(W1 + ((size_t)(r2 * NN + (k2 & 0xFFFF))) * NHID + q);
            float4 v3 = *(const float4*)(W1 + ((size_t)(r3 * NN + (k3 & 0xFFFF))) * NHID + q);
            atomicAdd(&acc[wave][(q + 0) * RR + r0], v0.x * m0);
            atomicAdd(&acc[wave][(q + 1) * RR + r0], v0.y * m0);
            atomicAdd(&acc[wave][(q + 2) * RR + r0], v0.z * m0);
            atomicAdd(&acc[wave][(q + 3) * RR + r0], v0.w * m0);
            if (lead) atomicAdd(&degL[wave][r0], m0);
            atomicAdd(&acc[wave][(q + 0) * RR + r1], v1.x * m1);
            atomicAdd(&acc[wave][(q + 1) * RR + r1], v1.y * m1);
            atomicAdd(&acc[wave][(q + 2) * RR + r1], v1.z * m1);
            atomicAdd(&acc[wave][(q + 3) * RR + r1], v1.w * m1);
            if (lead) atomicAdd(&degL[wave][r1], m1);
            atomicAdd(&acc[wave][(q + 0) * RR + r2], v2.x * m2);
            atomicAdd(&acc[wave][(q + 1) * RR + r2], v2.y * m2);
            atomicAdd(&acc[wave][(q + 2) * RR + r2], v2.z * m2);
            atomicAdd(&acc[wave][(q + 3) * RR + r2], v2.w * m2);
            if (lead) atomicAdd(&degL[wave][r2], m2);
            atomicAdd(&acc[wave][(q + 0) * RR + r3], v3.x * m3);
            atomicAdd(&acc[wave][(q + 1) * RR + r3], v3.y * m3);
            atomicAdd(&acc[wave][(q + 2) * RR + r3], v3.z * m3);
            atomicAdd(&acc[wave][(q + 3) * RR + r3], v3.w * m3);
            if (lead) atomicAdd(&degL[wave][r3], m3);
        }
    }
    __syncthreads();
    if (lane < RR) {            // deg -> 1/deg in place
        float d = degL[wave][lane];
        degL[wave][lane] = (d != 0.f) ? 1.f / d : 0.f;
    }
    __syncthreads();
    if (n < NN) {
        const int g = lane >> 4, hh = lane & 15;
        float sum = 0.f;
        for (int r = g; r < RR; r += 4)
            sum += acc[wave][hh * RR + r] * degL[wave][r];
        sum += __shfl_xor(sum, 16);
        sum += __shfl_xor(sum, 32);
        if (lane < NHID) h[n * NHID + lane] = fmaxf(sum + b1[lane], 0.f);
    }
}

// Layer-2 aggregation: 512 threads, 1 node/wave. Same 4-deep pipelined loop
// against h; scale by 1/deg; emit af row as packed bf16 pairs.
__global__ __launch_bounds__(512) void agg_kernel(
        const unsigned* __restrict__ ekey, const unsigned* __restrict__ cnt,
        const float* __restrict__ h, unsigned* __restrict__ af) {
    __shared__ float buf[NPBRH];               // [nd][hh*41 + r]
    __shared__ float degL[NPB * RR];
    __shared__ unsigned keyc[NPB][STRIDE];
    const int tid = threadIdx.x, wave = tid >> 6, lane = tid & 63;
    const int nbase = blockIdx.x * NPB;
    const int n = nbase + wave;

    for (int i = tid; i < NPBRH; i += 512) buf[i] = 0.f;
    if (tid < NPB * RR) degL[tid] = 0.f;
    {
        const unsigned* ek = ekey + (size_t)n * STRIDE;
        keyc[wave][lane]      = ek[lane];
        keyc[wave][64 + lane] = ek[64 + lane];
    }
    __syncthreads();

    {   // Phase A: accumulate; 4-deep branch-free
        const int deg = cnt[n];
        const int dm1 = deg - 1;
        const int g = lane >> 2, q = (lane & 3) * 4;
        const bool lead = (lane & 3) == 0;
        float* base = &buf[wave * RH];
        float* dl = &degL[wave * RR];
        for (int i = 0; i < deg; i += 64) {
            const int i0 = i + g;
            const int j0 = min(i0,      dm1), j1 = min(i0 + 16, dm1);
            const int j2 = min(i0 + 32, dm1), j3 = min(i0 + 48, dm1);
            const unsigned k0 = keyc[wave][j0], k1 = keyc[wave][j1];
            const unsigned k2 = keyc[wave][j2], k3 = keyc[wave][j3];
            const float m0 = (i0      < deg) ? 1.f : 0.f;
            const float m1 = (i0 + 16 < deg) ? 1.f : 0.f;
            const float m2 = (i0 + 32 < deg) ? 1.f : 0.f;
            const float m3 = (i0 + 48 < deg) ? 1.f : 0.f;
            const int r0 = k0 >> 16, r1 = k1 >> 16, r2 = k2 >> 16, r3 = k3 >> 16;
            float4 v0 = *(const float4*)(h + (k0 & 0xFFFF) * NHID + q);
            float4 v1 = *(const float4*)(h + (k1 & 0xFFFF) * NHID + q);
            float4 v2 = *(const float4*)(h + (k2 & 0xFFFF) * NHID + q);
            float4 v3 = *(const float4*)(h + (k3 & 0xFFFF) * NHID + q);
            atomicAdd(base + (q + 0) * RR + r0, v0.x * m0);
            atomicAdd(base + (q + 1) * RR + r0, v0.y * m0);
            atomicAdd(base + (q + 2) * RR + r0, v0.z * m0);
            atomicAdd(base + (q + 3) * RR + r0, v0.w * m0);
            if (lead) atomicAdd(dl + r0, m0);
            atomicAdd(base + (q + 0) * RR + r1, v1.x * m1);
            atomicAdd(base + (q + 1) * RR + r1, v1.y * m1);
            atomicAdd(base + (q + 2) * RR + r1, v1.z * m1);
            atomicAdd(base + (q + 3) * RR + r1, v1.w * m1);
            if (lead) atomicAdd(dl + r1, m1);
            atomicAdd(base + (q + 0) * RR + r2, v2.x * m2);
            atomicAdd(base + (q + 1) * RR + r2, v2.y * m2);
            atomicAdd(base + (q + 2) * RR + r2, v2.z * m2);
            atomicAdd(base + (q + 3) * RR + r2, v2.w * m2);
            if (lead) atomicAdd(dl + r2, m2);
            atomicAdd(base + (q + 0) * RR + r3, v3.x * m3);
            atomicAdd(base + (q + 1) * RR + r3, v3.y * m3);
            atomicAdd(base + (q + 2) * RR + r3, v3.z * m3);
            atomicAdd(base + (q + 3) * RR + r3, v3.w * m3);
            if (lead) atomicAdd(dl + r3, m3);
        }
    }
    __syncthreads();
    if (tid < NPB * RR) {                      // deg -> 1/deg
        float d = degL[tid];
        degL[tid] = (d != 0.f) ? 1.f / d : 0.f;
    }
    __syncthreads();

    {   // write af row: u32 idx -> bf16 pair (k=2*idx, 2*idx+1)
        unsigned* arow = af + (size_t)n * KU32;
        for (int idx = lane; idx < KU32; idx += 64) {
            int rh0 = 2 * idx, rh1 = rh0 + 1;
            float v0 = 0.f, v1 = 0.f;
            if (rh0 < RH) v0 = buf[wave * RH + (rh0 & 15) * RR + (rh0 >> 4)]
                             * degL[wave * RR + (rh0 >> 4)];
            if (rh1 < RH) v1 = buf[wave * RH + (rh1 & 15) * RR + (rh1 >> 4)]
                             * degL[wave * RR + (rh1 >> 4)];
            arow[idx] = bf16r(v0) | (bf16r(v1) << 16);
        }
    }
}

// Pre-pack W2 (fp32) per-lane contiguous: W2pk[(kb*64+lane)*8 + j] = W2[kb*8+j][lane]
__global__ void pack_kernel(const float* __restrict__ W2, float* __restrict__ W2pk) {
    int idx = blockIdx.x * blockDim.x + threadIdx.x;
    if (idx >= KB * 64 * 8) return;
    int j = idx & 7, lane = (idx >> 3) & 63, kb = idx >> 9;
    int k = kb * 8 + j;
    W2pk[idx] = (k < RH && lane < NCLASS) ? W2[k * NCLASS + lane] : 0.f;
}

// GEMM + log-softmax: wave = 8 nodes, lane = class. af rows via wave-uniform
// loads; W2pk via per-lane contiguous float4 pairs. No LDS.
__global__ __launch_bounds__(512) void gemm_kernel(
        const unsigned* __restrict__ af, const float* __restrict__ W2pk,
        const float* __restrict__ b2, float* __restrict__ out) {
    const int tid = threadIdx.x;
    const int wv = __builtin_amdgcn_readfirstlane(tid >> 6);
    const int lane = tid & 63;
    const int nbase = blockIdx.x * 64 + wv * 8;

    const uint4* a0 = (const uint4*)(af + (size_t)(nbase + 0) * KU32);
    const uint4* a1 = (const uint4*)(af + (size_t)(nbase + 1) * KU32);
    const uint4* a2 = (const uint4*)(af + (size_t)(nbase + 2) * KU32);
    const uint4* a3 = (const uint4*)(af + (size_t)(nbase + 3) * KU32);
    const uint4* a4 = (const uint4*)(af + (size_t)(nbase + 4) * KU32);
    const uint4* a5 = (const uint4*)(af + (size_t)(nbase + 5) * KU32);
    const uint4* a6 = (const uint4*)(af + (size_t)(nbase + 6) * KU32);
    const uint4* a7 = (const uint4*)(af + (size_t)(nbase + 7) * KU32);

    float acc[8];
    #pragma unroll
    for (int q = 0; q < 8; ++q) acc[q] = 0.f;

    const float* wbase = W2pk + (size_t)lane * 8;
    for (int kb = 0; kb < KB; ++kb) {
        float4 wA = *(const float4*)(wbase + (size_t)kb * 512);
        float4 wB = *(const float4*)(wbase + (size_t)kb * 512 + 4);
        uint4 a[8];
        a[0] = a0[kb]; a[1] = a1[kb]; a[2] = a2[kb]; a[3] = a3[kb];
        a[4] = a4[kb]; a[5] = a5[kb]; a[6] = a6[kb]; a[7] = a7[kb];
        #pragma unroll
        for (int q = 0; q < 8; ++q) {
            uint4 v = a[q];
            acc[q] += __uint_as_float(v.x << 16)         * wA.x
                    + __uint_as_float(v.x & 0xffff0000u) * wA.y
                    + __uint_as_float(v.y << 16)         * wA.z
                    + __uint_as_float(v.y & 0xffff0000u) * wA.w
                    + __uint_as_float(v.z << 16)         * wB.x
                    + __uint_as_float(v.z & 0xffff0000u) * wB.y
                    + __uint_as_float(v.w << 16)         * wB.z
                    + __uint_as_float(v.w & 0xffff0000u) * wB.w;
        }
    }

    const float bias = (lane < NCLASS) ? b2[lane] : 0.f;
    #pragma unroll
    for (int q = 0; q < 8; ++q) {
        const int n = nbase + q;
        if (n < NN) {
            float x = (lane < NCLASS) ? acc[q] + bias : -INFINITY;
            float m = x;
            #pragma unroll
            for (int off = 32; off; off >>= 1) m = fmaxf(m, __shfl_xor(m, off));
            float ex = (lane < NCLASS) ? expf(x - m) : 0.f;
            float ss = ex;
            #pragma unroll
            for (int off = 32; off; off >>= 1) ss += __shfl_xor(ss, off);
            float ls = logf(ss) + m;
            if (lane < NCLASS) out[n * NCLASS + lane] = x - ls;
        }
    }
}

extern "C" void kernel_launch(void* const* d_in, const int* in_sizes, int n_in,
                              void* d_out, int out_size, void* d_ws, size_t ws_size,
                              hipStream_t stream) {
    const int*   src = (const int*)d_in[0];
    const int*   rel = (const int*)d_in[1];
    const int*   dst = (const int*)d_in[2];
    const float* W1  = (const float*)d_in[3];
    const float* b1  = (const float*)d_in[4];
    const float* W2  = (const float*)d_in[5];
    const float* b2  = (const float*)d_in[6];
    float* out = (float*)d_out;

    unsigned* cnt  = (unsigned*)d_ws;                        // NN
    unsigned* ekey = cnt + NN;                               // NN*STRIDE (25.6 MB)
    float*    h    = (float*)(ekey + (size_t)NN * STRIDE);   // NN*NHID (3.2 MB)
    unsigned* af   = (unsigned*)(h + (size_t)NN * NHID);     // NROWS*KU32 (67.3 MB)
    float*    W2pk = (float*)(af + (size_t)NROWS * KU32);    // KB*512 (172 KB)

    const int blk = 256;
    init_kernel<<<(NN + blk - 1) / blk, blk, 0, stream>>>(cnt, ekey);
    scatter_kernel<<<(EB + blk - 1) / blk, blk, 0, stream>>>(src, rel, dst, cnt, ekey);
    pack_kernel<<<(KB * 512 + blk - 1) / blk, blk, 0, stream>>>(W2, W2pk);
    layer1_kernel<<<NN / WPB, blk, 0, stream>>>(ekey, cnt, W1, b1, h);
    agg_kernel<<<NN / NPB, 512, 0, stream>>>(ekey, cnt, h, af);
    gemm_kernel<<<(NN + 63) / 64, 512, 0, stream>>>(af, W2pk, b2, out);
}

// Round 10
// 813.084 us; speedup vs baseline: 1.5999x; 1.5999x over previous
//
#include <hip/hip_runtime.h>

#define NN     50000
#define NRELB  20
#define RR     (2*NRELB + 1)      // 41
#define NHID   16
#define NCLASS 50
#define EB     1600000
#define WPB    4                  // waves per block (layer1)
#define RH     (RR * NHID)        // 656
#define STRIDE 128                // static CSR bucket size
#define KPAD   672                // 656 padded to 42*16 (r=41 row is the pad)
#define KU32   (KPAD/2)           // 336 u32 (f16 pairs) per af row
#define KB     (KPAD/8)           // 84 k-blocks of 8
#define NROWS  50048              // 782*64 af rows (padded)
#define PM     72                 // padded k-stride (elems) for M and rT
#define AGW    4                  // agg: waves (= nodes) per block

using f16x8 = __attribute__((ext_vector_type(8))) _Float16;
using f32x4 = __attribute__((ext_vector_type(4))) float;

// Seed each node's bucket with its self-loop at slot 0.
__global__ void init_kernel(unsigned* __restrict__ cnt, unsigned* __restrict__ ekey) {
    int n = blockIdx.x * blockDim.x + threadIdx.x;
    if (n >= NN) return;
    cnt[n] = 1u;
    ekey[(size_t)n * STRIDE] = ((unsigned)(2 * NRELB) << 16) | (unsigned)n;
}

// One thread per base edge: emit forward + inverse into static buckets.
__global__ void scatter_kernel(const int* __restrict__ src, const int* __restrict__ rel,
                               const int* __restrict__ dst,
                               unsigned* __restrict__ cnt, unsigned* __restrict__ ekey) {
    int e = blockIdx.x * blockDim.x + threadIdx.x;
    if (e >= EB) return;
    int s = src[e], r = rel[e], o = dst[e];
    unsigned p1 = atomicAdd(&cnt[s], 1u);
    ekey[(size_t)s * STRIDE + p1] = ((unsigned)r << 16) | (unsigned)o;
    unsigned p2 = atomicAdd(&cnt[o], 1u);
    ekey[(size_t)o * STRIDE + p2] = ((unsigned)(r + NRELB) << 16) | (unsigned)s;
}

// Layer 1 (CONTROL, unchanged): one wave per node, h-major LDS [h*41+r],
// 2-deep pipelined edge loop with LDS atomics.
__global__ __launch_bounds__(256) void layer1_kernel(
        const unsigned* __restrict__ ekey, const unsigned* __restrict__ cnt,
        const float* __restrict__ W1, const float* __restrict__ b1,
        float* __restrict__ h) {
    __shared__ float acc[WPB][RH];      // [h*41 + r]
    __shared__ float degL[WPB][RR];
    const int wave = threadIdx.x >> 6, lane = threadIdx.x & 63;
    const int n = blockIdx.x * WPB + wave;
    for (int i = lane; i < RH; i += 64) acc[wave][i] = 0.f;
    if (lane < RR) degL[wave][lane] = 0.f;
    __syncthreads();
    if (n < NN) {
        const int deg = cnt[n];
        const int g = lane >> 2, q = (lane & 3) * 4;
        const unsigned* ek = ekey + (size_t)n * STRIDE;
        for (int i = g; i < deg; i += 32) {
            unsigned k0 = ek[i];
            int r0 = k0 >> 16, o0 = k0 & 0xFFFF;
            float4 v0 = *(const float4*)(W1 + ((size_t)(r0 * NN + o0)) * NHID + q);
            const bool has1 = (i + 16) < deg;
            unsigned k1 = 0; float4 v1 = v0; int r1 = 0;
            if (has1) {
                k1 = ek[i + 16];
                r1 = k1 >> 16;
                v1 = *(const float4*)(W1 + ((size_t)(r1 * NN + (k1 & 0xFFFF))) * NHID + q);
            }
            atomicAdd(&acc[wave][(q + 0) * RR + r0], v0.x);
            atomicAdd(&acc[wave][(q + 1) * RR + r0], v0.y);
            atomicAdd(&acc[wave][(q + 2) * RR + r0], v0.z);
            atomicAdd(&acc[wave][(q + 3) * RR + r0], v0.w);
            if ((lane & 3) == 0) atomicAdd(&degL[wave][r0], 1.f);
            if (has1) {
                atomicAdd(&acc[wave][(q + 0) * RR + r1], v1.x);
                atomicAdd(&acc[wave][(q + 1) * RR + r1], v1.y);
                atomicAdd(&acc[wave][(q + 2) * RR + r1], v1.z);
                atomicAdd(&acc[wave][(q + 3) * RR + r1], v1.w);
                if ((lane & 3) == 0) atomicAdd(&degL[wave][r1], 1.f);
            }
        }
    }
    __syncthreads();
    if (lane < RR) {            // deg -> 1/deg in place
        float d = degL[wave][lane];
        degL[wave][lane] = (d != 0.f) ? 1.f / d : 0.f;
    }
    __syncthreads();
    if (n < NN) {
        const int g = lane >> 4, hh = lane & 15;
        float sum = 0.f;
        for (int r = g; r < RR; r += 4)
            sum += acc[wave][hh * RR + r] * degL[wave][r];
        sum += __shfl_xor(sum, 16);
        sum += __shfl_xor(sum, 32);
        if (lane < NHID) h[n * NHID + lane] = fmaxf(sum + b1[lane], 0.f);
    }
}

// Layer-2 aggregation via per-node mini-MFMA: af[r][h] = M[48][64] @ rows[64][16].
// No LDS atomics in the hot path, no __syncthreads (waves independent).
// M[r][k]=1 iff edge k has relation r; stale/pad rT entries are killed by M=0.
// FIX (R9): rT zero-initialized once — uninit LDS could hold f16 NaN patterns,
// and 0*NaN = NaN through the MFMA K-reduction.
__global__ __launch_bounds__(256) void agg_kernel(
        const unsigned* __restrict__ ekey, const unsigned* __restrict__ cnt,
        const float* __restrict__ h, unsigned* __restrict__ af) {
    __shared__ __align__(16) _Float16 Mlds[AGW][48 * PM];
    __shared__ __align__(16) _Float16 rT[AGW][16 * PM];
    __shared__ float degL[AGW][48];
    const int wave = threadIdx.x >> 6, lane = threadIdx.x & 63;
    const int n = blockIdx.x * AGW + wave;
    const unsigned* ek = ekey + (size_t)n * STRIDE;
    const int deg = cnt[n];

    if (lane < 48) degL[wave][lane] = 0.f;
    {   // zero rT (16*PM f16 = 576 u32), wave-private
        unsigned* rz = (unsigned*)&rT[wave][0];
        #pragma unroll
        for (int t = 0; t < 9; ++t) rz[lane + t * 64] = 0u;
    }

    f32x4 d0 = {0.f, 0.f, 0.f, 0.f};
    f32x4 d1 = {0.f, 0.f, 0.f, 0.f};
    f32x4 d2 = {0.f, 0.f, 0.f, 0.f};
    const f16x8 Z = {};

    for (int c0 = 0; c0 < deg; c0 += 64) {
        // zero M[48][0..64)
        #pragma unroll
        for (int t = 0; t < 6; ++t) {
            int j = lane + t * 64;
            *(f16x8*)&Mlds[wave][(j >> 3) * PM + (j & 7) * 8] = Z;
        }
        const int degc = min(deg - c0, 64);

        // build M + degree histogram (race-free M write: distinct k columns)
        if (lane < degc) {
            unsigned key = ek[c0 + lane];
            int r = key >> 16;
            Mlds[wave][r * PM + lane] = (_Float16)1.f;
            atomicAdd(&degL[wave][r], 1.f);
        }

        // gather h rows -> rT (transposed, f16); clamped tail writes are
        // benign (same value) and masked by M=0.
        {
            const int g = lane >> 2, q = (lane & 3) * 4;
            for (int i = 0; i < degc; i += 16) {
                int kl = min(i + g, degc - 1);
                unsigned key = ek[c0 + kl];
                float4 v = *(const float4*)(h + (key & 0xFFFF) * NHID + q);
                rT[wave][(q + 0) * PM + kl] = (_Float16)v.x;
                rT[wave][(q + 1) * PM + kl] = (_Float16)v.y;
                rT[wave][(q + 2) * PM + kl] = (_Float16)v.z;
                rT[wave][(q + 3) * PM + kl] = (_Float16)v.w;
            }
        }

        // D[m=r][n=h] += A(M) * B(rows); A: m=lane&15, k=(lane>>4)*8+j;
        // B: n=lane&15, same k slice (rT is [h][k] so this is a b128 read).
        const int nkt = (degc > 32) ? 2 : 1;
        for (int kt = 0; kt < nkt; ++kt) {
            const int ko = kt * 32 + (lane >> 4) * 8;
            f16x8 b  = *(const f16x8*)&rT[wave][(lane & 15) * PM + ko];
            f16x8 a0 = *(const f16x8*)&Mlds[wave][((lane & 15)) * PM + ko];
            f16x8 a1 = *(const f16x8*)&Mlds[wave][(16 + (lane & 15)) * PM + ko];
            f16x8 a2 = *(const f16x8*)&Mlds[wave][(32 + (lane & 15)) * PM + ko];
            d0 = __builtin_amdgcn_mfma_f32_16x16x32_f16(a0, b, d0, 0, 0, 0);
            d1 = __builtin_amdgcn_mfma_f32_16x16x32_f16(a1, b, d1, 0, 0, 0);
            d2 = __builtin_amdgcn_mfma_f32_16x16x32_f16(a2, b, d2, 0, 0, 0);
        }
    }

    // epilogue: scale by 1/deg_r, store af row as f16 (r==41 row = pad zeros)
    _Float16* arow = (_Float16*)af + (size_t)n * KPAD;
    const int hh = lane & 15, rg = lane >> 4;
    #pragma unroll
    for (int mt = 0; mt < 3; ++mt) {
        f32x4 dv = (mt == 0) ? d0 : (mt == 1) ? d1 : d2;
        #pragma unroll
        for (int c = 0; c < 4; ++c) {
            int r = mt * 16 + rg * 4 + c;
            if (r <= RR) {
                float val = 0.f;
                if (r < RR) {
                    float dgc = degL[wave][r];
                    val = (dgc != 0.f) ? dv[c] / dgc : 0.f;
                }
                arow[r * 16 + hh] = (_Float16)val;
            }
        }
    }
}

// Pre-pack W2 (fp32) per-lane contiguous: W2pk[(kb*64+lane)*8 + j] = W2[kb*8+j][lane]
__global__ void pack_kernel(const float* __restrict__ W2, float* __restrict__ W2pk) {
    int idx = blockIdx.x * blockDim.x + threadIdx.x;
    if (idx >= KB * 64 * 8) return;
    int j = idx & 7, lane = (idx >> 3) & 63, kb = idx >> 9;
    int k = kb * 8 + j;
    W2pk[idx] = (k < RH && lane < NCLASS) ? W2[k * NCLASS + lane] : 0.f;
}

__device__ __forceinline__ void hacc(float& acc, unsigned u, float w0, float w1) {
    union { unsigned v; _Float16 x[2]; } t; t.v = u;
    acc += (float)t.x[0] * w0 + (float)t.x[1] * w1;
}

// GEMM + log-softmax: wave = 8 nodes, lane = class. af rows (f16) via
// wave-uniform loads; W2pk via per-lane contiguous float4 pairs. No LDS.
__global__ __launch_bounds__(512) void gemm_kernel(
        const unsigned* __restrict__ af, const float* __restrict__ W2pk,
        const float* __restrict__ b2, float* __restrict__ out) {
    const int tid = threadIdx.x;
    const int wv = __builtin_amdgcn_readfirstlane(tid >> 6);
    const int lane = tid & 63;
    const int nbase = blockIdx.x * 64 + wv * 8;

    const uint4* a0 = (const uint4*)(af + (size_t)(nbase + 0) * KU32);
    const uint4* a1 = (const uint4*)(af + (size_t)(nbase + 1) * KU32);
    const uint4* a2 = (const uint4*)(af + (size_t)(nbase + 2) * KU32);
    const uint4* a3 = (const uint4*)(af + (size_t)(nbase + 3) * KU32);
    const uint4* a4 = (const uint4*)(af + (size_t)(nbase + 4) * KU32);
    const uint4* a5 = (const uint4*)(af + (size_t)(nbase + 5) * KU32);
    const uint4* a6 = (const uint4*)(af + (size_t)(nbase + 6) * KU32);
    const uint4* a7 = (const uint4*)(af + (size_t)(nbase + 7) * KU32);

    float acc[8];
    #pragma unroll
    for (int q = 0; q < 8; ++q) acc[q] = 0.f;

    const float* wbase = W2pk + (size_t)lane * 8;
    for (int kb = 0; kb < KB; ++kb) {
        float4 wA = *(const float4*)(wbase + (size_t)kb * 512);
        float4 wB = *(const float4*)(wbase + (size_t)kb * 512 + 4);
        uint4 a[8];
        a[0] = a0[kb]; a[1] = a1[kb]; a[2] = a2[kb]; a[3] = a3[kb];
        a[4] = a4[kb]; a[5] = a5[kb]; a[6] = a6[kb]; a[7] = a7[kb];
        #pragma unroll
        for (int q = 0; q < 8; ++q) {
            hacc(acc[q], a[q].x, wA.x, wA.y);
            hacc(acc[q], a[q].y, wA.z, wA.w);
            hacc(acc[q], a[q].z, wB.x, wB.y);
            hacc(acc[q], a[q].w, wB.z, wB.w);
        }
    }

    const float bias = (lane < NCLASS) ? b2[lane] : 0.f;
    #pragma unroll
    for (int q = 0; q < 8; ++q) {
        const int n = nbase + q;
        if (n < NN) {
            float x = (lane < NCLASS) ? acc[q] + bias : -INFINITY;
            float m = x;
            #pragma unroll
            for (int off = 32; off; off >>= 1) m = fmaxf(m, __shfl_xor(m, off));
            float ex = (lane < NCLASS) ? expf(x - m) : 0.f;
            float ss = ex;
            #pragma unroll
            for (int off = 32; off; off >>= 1) ss += __shfl_xor(ss, off);
            float ls = logf(ss) + m;
            if (lane < NCLASS) out[n * NCLASS + lane] = x - ls;
        }
    }
}

extern "C" void kernel_launch(void* const* d_in, const int* in_sizes, int n_in,
                              void* d_out, int out_size, void* d_ws, size_t ws_size,
                              hipStream_t stream) {
    const int*   src = (const int*)d_in[0];
    const int*   rel = (const int*)d_in[1];
    const int*   dst = (const int*)d_in[2];
    const float* W1  = (const float*)d_in[3];
    const float* b1  = (const float*)d_in[4];
    const float* W2  = (const float*)d_in[5];
    const float* b2  = (const float*)d_in[6];
    float* out = (float*)d_out;

    unsigned* cnt  = (unsigned*)d_ws;                        // NN
    unsigned* ekey = cnt + NN;                               // NN*STRIDE (25.6 MB)
    float*    h    = (float*)(ekey + (size_t)NN * STRIDE);   // NN*NHID (3.2 MB)
    unsigned* af   = (unsigned*)(h + (size_t)NN * NHID);     // NROWS*KU32 (67.3 MB)
    float*    W2pk = (float*)(af + (size_t)NROWS * KU32);    // KB*512 (172 KB)

    const int blk = 256;
    init_kernel<<<(NN + blk - 1) / blk, blk, 0, stream>>>(cnt, ekey);
    scatter_kernel<<<(EB + blk - 1) / blk, blk, 0, stream>>>(src, rel, dst, cnt, ekey);
    pack_kernel<<<(KB * 512 + blk - 1) / blk, blk, 0, stream>>>(W2, W2pk);
    layer1_kernel<<<NN / WPB, blk, 0, stream>>>(ekey, cnt, W1, b1, h);
    agg_kernel<<<NN / AGW, blk, 0, stream>>>(ekey, cnt, h, af);
    gemm_kernel<<<(NN + 63) / 64, 512, 0, stream>>>(af, W2pk, b2, out);
}

// Round 11
// 638.635 us; speedup vs baseline: 2.0369x; 1.2732x over previous
//
#include <hip/hip_runtime.h>

#define NN     50000
#define NRELB  20
#define RR     (2*NRELB + 1)      // 41
#define NHID   16
#define NCLASS 50
#define EB     1600000
#define RH     (RR * NHID)        // 656
#define STRIDE 128                // static CSR bucket size
#define KPAD   672                // 656 padded to 42*16 (r=41 row is the pad)
#define KU32   (KPAD/2)           // 336 u32 (f16 pairs) per af row
#define KB     (KPAD/8)           // 84 k-blocks of 8
#define NROWS  50048              // 782*64 af rows (padded)
#define PM     72                 // padded k-stride (elems) for M and rT
#define AGW    4                  // waves (= nodes) per block (layer1 + agg)

using f16x8 = __attribute__((ext_vector_type(8))) _Float16;
using f32x4 = __attribute__((ext_vector_type(4))) float;

// Seed each node's bucket with its self-loop at slot 0.
__global__ void init_kernel(unsigned* __restrict__ cnt, unsigned* __restrict__ ekey) {
    int n = blockIdx.x * blockDim.x + threadIdx.x;
    if (n >= NN) return;
    cnt[n] = 1u;
    ekey[(size_t)n * STRIDE] = ((unsigned)(2 * NRELB) << 16) | (unsigned)n;
}

// One thread per base edge: emit forward + inverse into static buckets.
__global__ void scatter_kernel(const int* __restrict__ src, const int* __restrict__ rel,
                               const int* __restrict__ dst,
                               unsigned* __restrict__ cnt, unsigned* __restrict__ ekey) {
    int e = blockIdx.x * blockDim.x + threadIdx.x;
    if (e >= EB) return;
    int s = src[e], r = rel[e], o = dst[e];
    unsigned p1 = atomicAdd(&cnt[s], 1u);
    ekey[(size_t)s * STRIDE + p1] = ((unsigned)r << 16) | (unsigned)o;
    unsigned p2 = atomicAdd(&cnt[o], 1u);
    ekey[(size_t)o * STRIDE + p2] = ((unsigned)(r + NRELB) << 16) | (unsigned)s;
}

// Layer 1 via per-node mini-MFMA (ported from agg): acc[r][h] = M[48][64] @ W1rows[64][16].
// Epilogue: scale rows by 1/deg_r, SUM over r, +bias, ReLU -> h[n][16] (f32).
// No LDS atomics in the hot path, no __syncthreads (waves independent).
__global__ __launch_bounds__(256) void layer1_kernel(
        const unsigned* __restrict__ ekey, const unsigned* __restrict__ cnt,
        const float* __restrict__ W1, const float* __restrict__ b1,
        float* __restrict__ h) {
    __shared__ __align__(16) _Float16 Mlds[AGW][48 * PM];
    __shared__ __align__(16) _Float16 rT[AGW][16 * PM];
    __shared__ float degL[AGW][48];
    const int wave = threadIdx.x >> 6, lane = threadIdx.x & 63;
    const int n = blockIdx.x * AGW + wave;
    const unsigned* ek = ekey + (size_t)n * STRIDE;
    const int deg = cnt[n];

    if (lane < 48) degL[wave][lane] = 0.f;
    {   // zero rT (16*PM f16 = 576 u32), wave-private
        unsigned* rz = (unsigned*)&rT[wave][0];
        #pragma unroll
        for (int t = 0; t < 9; ++t) rz[lane + t * 64] = 0u;
    }

    f32x4 d0 = {0.f, 0.f, 0.f, 0.f};
    f32x4 d1 = {0.f, 0.f, 0.f, 0.f};
    f32x4 d2 = {0.f, 0.f, 0.f, 0.f};
    const f16x8 Z = {};

    for (int c0 = 0; c0 < deg; c0 += 64) {
        // zero M[48][0..64)
        #pragma unroll
        for (int t = 0; t < 6; ++t) {
            int j = lane + t * 64;
            *(f16x8*)&Mlds[wave][(j >> 3) * PM + (j & 7) * 8] = Z;
        }
        const int degc = min(deg - c0, 64);

        // build M + degree histogram (race-free M write: distinct k columns)
        if (lane < degc) {
            unsigned key = ek[c0 + lane];
            int r = key >> 16;
            Mlds[wave][r * PM + lane] = (_Float16)1.f;
            atomicAdd(&degL[wave][r], 1.f);
        }

        // gather W1 rows -> rT (transposed, f16); clamped tail writes are
        // benign (same value) and masked by M=0.
        {
            const int g = lane >> 2, q = (lane & 3) * 4;
            for (int i = 0; i < degc; i += 16) {
                int kl = min(i + g, degc - 1);
                unsigned key = ek[c0 + kl];
                int r = key >> 16, o = key & 0xFFFF;
                float4 v = *(const float4*)(W1 + ((size_t)(r * NN + o)) * NHID + q);
                rT[wave][(q + 0) * PM + kl] = (_Float16)v.x;
                rT[wave][(q + 1) * PM + kl] = (_Float16)v.y;
                rT[wave][(q + 2) * PM + kl] = (_Float16)v.z;
                rT[wave][(q + 3) * PM + kl] = (_Float16)v.w;
            }
        }

        // D[m=r][n=h] += A(M) * B(rows)
        const int nkt = (degc > 32) ? 2 : 1;
        for (int kt = 0; kt < nkt; ++kt) {
            const int ko = kt * 32 + (lane >> 4) * 8;
            f16x8 b  = *(const f16x8*)&rT[wave][(lane & 15) * PM + ko];
            f16x8 a0 = *(const f16x8*)&Mlds[wave][((lane & 15)) * PM + ko];
            f16x8 a1 = *(const f16x8*)&Mlds[wave][(16 + (lane & 15)) * PM + ko];
            f16x8 a2 = *(const f16x8*)&Mlds[wave][(32 + (lane & 15)) * PM + ko];
            d0 = __builtin_amdgcn_mfma_f32_16x16x32_f16(a0, b, d0, 0, 0, 0);
            d1 = __builtin_amdgcn_mfma_f32_16x16x32_f16(a1, b, d1, 0, 0, 0);
            d2 = __builtin_amdgcn_mfma_f32_16x16x32_f16(a2, b, d2, 0, 0, 0);
        }
    }

    // epilogue: partial_h = sum_r acc[r][h] / deg_r over this lane's 12 r-rows,
    // then reduce across the 4 lane-groups; +bias, ReLU, store f32.
    float partial = 0.f;
    const int rg = lane >> 4;
    #pragma unroll
    for (int mt = 0; mt < 3; ++mt) {
        f32x4 dv = (mt == 0) ? d0 : (mt == 1) ? d1 : d2;
        #pragma unroll
        for (int c = 0; c < 4; ++c) {
            int r = mt * 16 + rg * 4 + c;
            if (r < RR) {
                float dgc = degL[wave][r];
                partial += (dgc != 0.f) ? dv[c] / dgc : 0.f;
            }
        }
    }
    partial += __shfl_xor(partial, 16);
    partial += __shfl_xor(partial, 32);
    if (lane < NHID) h[n * NHID + lane] = fmaxf(partial + b1[lane], 0.f);
}

// Layer-2 aggregation via per-node mini-MFMA: af[r][h] = M[48][64] @ rows[64][16].
__global__ __launch_bounds__(256) void agg_kernel(
        const unsigned* __restrict__ ekey, const unsigned* __restrict__ cnt,
        const float* __restrict__ h, unsigned* __restrict__ af) {
    __shared__ __align__(16) _Float16 Mlds[AGW][48 * PM];
    __shared__ __align__(16) _Float16 rT[AGW][16 * PM];
    __shared__ float degL[AGW][48];
    const int wave = threadIdx.x >> 6, lane = threadIdx.x & 63;
    const int n = blockIdx.x * AGW + wave;
    const unsigned* ek = ekey + (size_t)n * STRIDE;
    const int deg = cnt[n];

    if (lane < 48) degL[wave][lane] = 0.f;
    {   // zero rT
        unsigned* rz = (unsigned*)&rT[wave][0];
        #pragma unroll
        for (int t = 0; t < 9; ++t) rz[lane + t * 64] = 0u;
    }

    f32x4 d0 = {0.f, 0.f, 0.f, 0.f};
    f32x4 d1 = {0.f, 0.f, 0.f, 0.f};
    f32x4 d2 = {0.f, 0.f, 0.f, 0.f};
    const f16x8 Z = {};

    for (int c0 = 0; c0 < deg; c0 += 64) {
        #pragma unroll
        for (int t = 0; t < 6; ++t) {
            int j = lane + t * 64;
            *(f16x8*)&Mlds[wave][(j >> 3) * PM + (j & 7) * 8] = Z;
        }
        const int degc = min(deg - c0, 64);

        if (lane < degc) {
            unsigned key = ek[c0 + lane];
            int r = key >> 16;
            Mlds[wave][r * PM + lane] = (_Float16)1.f;
            atomicAdd(&degL[wave][r], 1.f);
        }

        {
            const int g = lane >> 2, q = (lane & 3) * 4;
            for (int i = 0; i < degc; i += 16) {
                int kl = min(i + g, degc - 1);
                unsigned key = ek[c0 + kl];
                float4 v = *(const float4*)(h + (key & 0xFFFF) * NHID + q);
                rT[wave][(q + 0) * PM + kl] = (_Float16)v.x;
                rT[wave][(q + 1) * PM + kl] = (_Float16)v.y;
                rT[wave][(q + 2) * PM + kl] = (_Float16)v.z;
                rT[wave][(q + 3) * PM + kl] = (_Float16)v.w;
            }
        }

        const int nkt = (degc > 32) ? 2 : 1;
        for (int kt = 0; kt < nkt; ++kt) {
            const int ko = kt * 32 + (lane >> 4) * 8;
            f16x8 b  = *(const f16x8*)&rT[wave][(lane & 15) * PM + ko];
            f16x8 a0 = *(const f16x8*)&Mlds[wave][((lane & 15)) * PM + ko];
            f16x8 a1 = *(const f16x8*)&Mlds[wave][(16 + (lane & 15)) * PM + ko];
            f16x8 a2 = *(const f16x8*)&Mlds[wave][(32 + (lane & 15)) * PM + ko];
            d0 = __builtin_amdgcn_mfma_f32_16x16x32_f16(a0, b, d0, 0, 0, 0);
            d1 = __builtin_amdgcn_mfma_f32_16x16x32_f16(a1, b, d1, 0, 0, 0);
            d2 = __builtin_amdgcn_mfma_f32_16x16x32_f16(a2, b, d2, 0, 0, 0);
        }
    }

    // epilogue: scale by 1/deg_r, store af row as f16 (r==41 row = pad zeros)
    _Float16* arow = (_Float16*)af + (size_t)n * KPAD;
    const int hh = lane & 15, rg = lane >> 4;
    #pragma unroll
    for (int mt = 0; mt < 3; ++mt) {
        f32x4 dv = (mt == 0) ? d0 : (mt == 1) ? d1 : d2;
        #pragma unroll
        for (int c = 0; c < 4; ++c) {
            int r = mt * 16 + rg * 4 + c;
            if (r <= RR) {
                float val = 0.f;
                if (r < RR) {
                    float dgc = degL[wave][r];
                    val = (dgc != 0.f) ? dv[c] / dgc : 0.f;
                }
                arow[r * 16 + hh] = (_Float16)val;
            }
        }
    }
}

// Pre-pack W2 (fp32) per-lane contiguous: W2pk[(kb*64+lane)*8 + j] = W2[kb*8+j][lane]
__global__ void pack_kernel(const float* __restrict__ W2, float* __restrict__ W2pk) {
    int idx = blockIdx.x * blockDim.x + threadIdx.x;
    if (idx >= KB * 64 * 8) return;
    int j = idx & 7, lane = (idx >> 3) & 63, kb = idx >> 9;
    int k = kb * 8 + j;
    W2pk[idx] = (k < RH && lane < NCLASS) ? W2[k * NCLASS + lane] : 0.f;
}

__device__ __forceinline__ void hacc(float& acc, unsigned u, float w0, float w1) {
    union { unsigned v; _Float16 x[2]; } t; t.v = u;
    acc += (float)t.x[0] * w0 + (float)t.x[1] * w1;
}

// GEMM + log-softmax: wave = 8 nodes, lane = class. af rows (f16) via
// wave-uniform loads; W2pk via per-lane contiguous float4 pairs. No LDS.
__global__ __launch_bounds__(512) void gemm_kernel(
        const unsigned* __restrict__ af, const float* __restrict__ W2pk,
        const float* __restrict__ b2, float* __restrict__ out) {
    const int tid = threadIdx.x;
    const int wv = __builtin_amdgcn_readfirstlane(tid >> 6);
    const int lane = tid & 63;
    const int nbase = blockIdx.x * 64 + wv * 8;

    const uint4* a0 = (const uint4*)(af + (size_t)(nbase + 0) * KU32);
    const uint4* a1 = (const uint4*)(af + (size_t)(nbase + 1) * KU32);
    const uint4* a2 = (const uint4*)(af + (size_t)(nbase + 2) * KU32);
    const uint4* a3 = (const uint4*)(af + (size_t)(nbase + 3) * KU32);
    const uint4* a4 = (const uint4*)(af + (size_t)(nbase + 4) * KU32);
    const uint4* a5 = (const uint4*)(af + (size_t)(nbase + 5) * KU32);
    const uint4* a6 = (const uint4*)(af + (size_t)(nbase + 6) * KU32);
    const uint4* a7 = (const uint4*)(af + (size_t)(nbase + 7) * KU32);

    float acc[8];
    #pragma unroll
    for (int q = 0; q < 8; ++q) acc[q] = 0.f;

    const float* wbase = W2pk + (size_t)lane * 8;
    for (int kb = 0; kb < KB; ++kb) {
        float4 wA = *(const float4*)(wbase + (size_t)kb * 512);
        float4 wB = *(const float4*)(wbase + (size_t)kb * 512 + 4);
        uint4 a[8];
        a[0] = a0[kb]; a[1] = a1[kb]; a[2] = a2[kb]; a[3] = a3[kb];
        a[4] = a4[kb]; a[5] = a5[kb]; a[6] = a6[kb]; a[7] = a7[kb];
        #pragma unroll
        for (int q = 0; q < 8; ++q) {
            hacc(acc[q], a[q].x, wA.x, wA.y);
            hacc(acc[q], a[q].y, wA.z, wA.w);
            hacc(acc[q], a[q].z, wB.x, wB.y);
            hacc(acc[q], a[q].w, wB.z, wB.w);
        }
    }

    const float bias = (lane < NCLASS) ? b2[lane] : 0.f;
    #pragma unroll
    for (int q = 0; q < 8; ++q) {
        const int n = nbase + q;
        if (n < NN) {
            float x = (lane < NCLASS) ? acc[q] + bias : -INFINITY;
            float m = x;
            #pragma unroll
            for (int off = 32; off; off >>= 1) m = fmaxf(m, __shfl_xor(m, off));
            float ex = (lane < NCLASS) ? expf(x - m) : 0.f;
            float ss = ex;
            #pragma unroll
            for (int off = 32; off; off >>= 1) ss += __shfl_xor(ss, off);
            float ls = logf(ss) + m;
            if (lane < NCLASS) out[n * NCLASS + lane] = x - ls;
        }
    }
}

extern "C" void kernel_launch(void* const* d_in, const int* in_sizes, int n_in,
                              void* d_out, int out_size, void* d_ws, size_t ws_size,
                              hipStream_t stream) {
    const int*   src = (const int*)d_in[0];
    const int*   rel = (const int*)d_in[1];
    const int*   dst = (const int*)d_in[2];
    const float* W1  = (const float*)d_in[3];
    const float* b1  = (const float*)d_in[4];
    const float* W2  = (const float*)d_in[5];
    const float* b2  = (const float*)d_in[6];
    float* out = (float*)d_out;

    unsigned* cnt  = (unsigned*)d_ws;                        // NN
    unsigned* ekey = cnt + NN;                               // NN*STRIDE (25.6 MB)
    float*    h    = (float*)(ekey + (size_t)NN * STRIDE);   // NN*NHID (3.2 MB)
    unsigned* af   = (unsigned*)(h + (size_t)NN * NHID);     // NROWS*KU32 (67.3 MB)
    float*    W2pk = (float*)(af + (size_t)NROWS * KU32);    // KB*512 (172 KB)

    const int blk = 256;
    init_kernel<<<(NN + blk - 1) / blk, blk, 0, stream>>>(cnt, ekey);
    scatter_kernel<<<(EB + blk - 1) / blk, blk, 0, stream>>>(src, rel, dst, cnt, ekey);
    pack_kernel<<<(KB * 512 + blk - 1) / blk, blk, 0, stream>>>(W2, W2pk);
    layer1_kernel<<<NN / AGW, blk, 0, stream>>>(ekey, cnt, W1, b1, h);
    agg_kernel<<<NN / AGW, blk, 0, stream>>>(ekey, cnt, h, af);
    gemm_kernel<<<(NN + 63) / 64, 512, 0, stream>>>(af, W2pk, b2, out);
}

// Round 12
// 533.951 us; speedup vs baseline: 2.4362x; 1.1961x over previous
//
#include <hip/hip_runtime.h>

#define NN     50000
#define NRELB  20
#define RR     (2*NRELB + 1)      // 41
#define NHID   16
#define NCLASS 50
#define EB     1600000
#define RH     (RR * NHID)        // 656
#define NSEG   8                  // bucket segments (per ~XCD), 1 line each
#define SLOTS  16                 // slots per segment (64 B line)
#define BCAP   (NSEG * SLOTS)     // 128 >= max node degree (~117)
#define KPAD   672                // 656 padded to 42*16 (r=41 row is the pad)
#define KU32   (KPAD/2)           // 336 u32 (f16 pairs) per af row
#define KB     (KPAD/8)           // 84 k-blocks of 8
#define NROWS  50048              // 782*64 af rows (padded)
#define PM     72                 // padded k-stride (elems) for M and rT
#define AGW    4                  // waves (= nodes) per block (layer1 + agg)

using f16x8 = __attribute__((ext_vector_type(8))) _Float16;
using f32x4 = __attribute__((ext_vector_type(4))) float;

// Seed each node's bucket: segment 0 slot 0 = self-loop; zero all counters.
__global__ void init_kernel(unsigned* __restrict__ cnt, unsigned* __restrict__ ekey) {
    int n = blockIdx.x * blockDim.x + threadIdx.x;
    if (n >= NN) return;
    unsigned* c = cnt + (size_t)n * NSEG;
    #pragma unroll
    for (int g = 0; g < NSEG; ++g) c[g] = (g == 0) ? 1u : 0u;
    ekey[(size_t)n * BCAP] = ((unsigned)(2 * NRELB) << 16) | (unsigned)n;
}

// One thread per base edge: emit forward + inverse. Segment picked by
// blockIdx&7 (~XCD id) so each 64B segment line is written XCD-locally;
// full segments spill to the next (probing) — correct for ANY block->XCD map.
__global__ void scatter_kernel(const int* __restrict__ src, const int* __restrict__ rel,
                               const int* __restrict__ dst,
                               unsigned* __restrict__ cnt, unsigned* __restrict__ ekey) {
    int e = blockIdx.x * blockDim.x + threadIdx.x;
    if (e >= EB) return;
    const unsigned g0 = (unsigned)blockIdx.x & 7u;
    int s = __builtin_nontemporal_load(src + e);
    int r = __builtin_nontemporal_load(rel + e);
    int o = __builtin_nontemporal_load(dst + e);

    unsigned key = ((unsigned)r << 16) | (unsigned)o;     // forward -> bucket s
    unsigned g = g0;
    for (int t = 0; t < 64; ++t) {
        unsigned p = atomicAdd(&cnt[(size_t)s * NSEG + g], 1u);
        if (p < SLOTS) { ekey[((size_t)s * NSEG + g) * SLOTS + p] = key; break; }
        g = (g + 1) & 7u;
    }
    key = ((unsigned)(r + NRELB) << 16) | (unsigned)s;    // inverse -> bucket o
    g = g0;
    for (int t = 0; t < 64; ++t) {
        unsigned p = atomicAdd(&cnt[(size_t)o * NSEG + g], 1u);
        if (p < SLOTS) { ekey[((size_t)o * NSEG + g) * SLOTS + p] = key; break; }
        g = (g + 1) & 7u;
    }
}

// Compact a node's segmented bucket into a dense LDS key list (wave-private).
// Returns deg. All cnt loads are wave-uniform.
__device__ __forceinline__ int compact_keys(const unsigned* __restrict__ cnt,
                                            const unsigned* __restrict__ ekey,
                                            int n, int lane, unsigned* keyd) {
    const unsigned* cb = cnt + (size_t)n * NSEG;
    const unsigned* eb = ekey + (size_t)n * BCAP;
    int c0 = min((int)cb[0], SLOTS), c1 = min((int)cb[1], SLOTS);
    int c2 = min((int)cb[2], SLOTS), c3 = min((int)cb[3], SLOTS);
    int c4 = min((int)cb[4], SLOTS), c5 = min((int)cb[5], SLOTS);
    int c6 = min((int)cb[6], SLOTS), c7 = min((int)cb[7], SLOTS);
    int o1 = c0, o2 = o1 + c1, o3 = o2 + c2, o4 = o3 + c3;
    int o5 = o4 + c4, o6 = o5 + c5, o7 = o6 + c6;
    int deg = o7 + c7;
    const int gi = lane >> 4, sl = lane & 15;
    {   // segments 0..3
        int cg = gi == 0 ? c0 : gi == 1 ? c1 : gi == 2 ? c2 : c3;
        int og = gi == 0 ? 0  : gi == 1 ? o1 : gi == 2 ? o2 : o3;
        if (sl < cg) keyd[og + sl] = eb[gi * SLOTS + sl];
    }
    {   // segments 4..7
        int cg = gi == 0 ? c4 : gi == 1 ? c5 : gi == 2 ? c6 : c7;
        int og = gi == 0 ? o4 : gi == 1 ? o5 : gi == 2 ? o6 : o7;
        if (sl < cg) keyd[og + sl] = eb[(4 + gi) * SLOTS + sl];
    }
    return deg;
}

// Layer 1 via per-node mini-MFMA: acc[r][h] = M[48][64] @ W1rows[64][16].
// Epilogue: scale rows by 1/deg_r, SUM over r, +bias, ReLU -> h[n][16] (f32).
__global__ __launch_bounds__(256) void layer1_kernel(
        const unsigned* __restrict__ ekey, const unsigned* __restrict__ cnt,
        const float* __restrict__ W1, const float* __restrict__ b1,
        float* __restrict__ h) {
    __shared__ __align__(16) _Float16 Mlds[AGW][48 * PM];
    __shared__ __align__(16) _Float16 rT[AGW][16 * PM];
    __shared__ unsigned keyd[AGW][BCAP];
    __shared__ float degL[AGW][48];
    const int wave = threadIdx.x >> 6, lane = threadIdx.x & 63;
    const int n = blockIdx.x * AGW + wave;

    if (lane < 48) degL[wave][lane] = 0.f;
    {   // zero rT (16*PM f16 = 576 u32), wave-private
        unsigned* rz = (unsigned*)&rT[wave][0];
        #pragma unroll
        for (int t = 0; t < 9; ++t) rz[lane + t * 64] = 0u;
    }
    const int deg = compact_keys(cnt, ekey, n, lane, keyd[wave]);

    f32x4 d0 = {0.f, 0.f, 0.f, 0.f};
    f32x4 d1 = {0.f, 0.f, 0.f, 0.f};
    f32x4 d2 = {0.f, 0.f, 0.f, 0.f};
    const f16x8 Z = {};

    for (int c0 = 0; c0 < deg; c0 += 64) {
        #pragma unroll
        for (int t = 0; t < 6; ++t) {
            int j = lane + t * 64;
            *(f16x8*)&Mlds[wave][(j >> 3) * PM + (j & 7) * 8] = Z;
        }
        const int degc = min(deg - c0, 64);

        if (lane < degc) {
            unsigned key = keyd[wave][c0 + lane];
            int r = key >> 16;
            Mlds[wave][r * PM + lane] = (_Float16)1.f;
            atomicAdd(&degL[wave][r], 1.f);
        }

        {   // gather W1 rows -> rT (transposed, f16)
            const int g = lane >> 2, q = (lane & 3) * 4;
            for (int i = 0; i < degc; i += 16) {
                int kl = min(i + g, degc - 1);
                unsigned key = keyd[wave][c0 + kl];
                int r = key >> 16, o = key & 0xFFFF;
                float4 v = *(const float4*)(W1 + ((size_t)(r * NN + o)) * NHID + q);
                rT[wave][(q + 0) * PM + kl] = (_Float16)v.x;
                rT[wave][(q + 1) * PM + kl] = (_Float16)v.y;
                rT[wave][(q + 2) * PM + kl] = (_Float16)v.z;
                rT[wave][(q + 3) * PM + kl] = (_Float16)v.w;
            }
        }

        const int nkt = (degc > 32) ? 2 : 1;
        for (int kt = 0; kt < nkt; ++kt) {
            const int ko = kt * 32 + (lane >> 4) * 8;
            f16x8 b  = *(const f16x8*)&rT[wave][(lane & 15) * PM + ko];
            f16x8 a0 = *(const f16x8*)&Mlds[wave][((lane & 15)) * PM + ko];
            f16x8 a1 = *(const f16x8*)&Mlds[wave][(16 + (lane & 15)) * PM + ko];
            f16x8 a2 = *(const f16x8*)&Mlds[wave][(32 + (lane & 15)) * PM + ko];
            d0 = __builtin_amdgcn_mfma_f32_16x16x32_f16(a0, b, d0, 0, 0, 0);
            d1 = __builtin_amdgcn_mfma_f32_16x16x32_f16(a1, b, d1, 0, 0, 0);
            d2 = __builtin_amdgcn_mfma_f32_16x16x32_f16(a2, b, d2, 0, 0, 0);
        }
    }

    float partial = 0.f;
    const int rg = lane >> 4;
    #pragma unroll
    for (int mt = 0; mt < 3; ++mt) {
        f32x4 dv = (mt == 0) ? d0 : (mt == 1) ? d1 : d2;
        #pragma unroll
        for (int c = 0; c < 4; ++c) {
            int r = mt * 16 + rg * 4 + c;
            if (r < RR) {
                float dgc = degL[wave][r];
                partial += (dgc != 0.f) ? dv[c] / dgc : 0.f;
            }
        }
    }
    partial += __shfl_xor(partial, 16);
    partial += __shfl_xor(partial, 32);
    if (lane < NHID) h[n * NHID + lane] = fmaxf(partial + b1[lane], 0.f);
}

// Layer-2 aggregation via per-node mini-MFMA: af[r][h] = M[48][64] @ rows[64][16].
__global__ __launch_bounds__(256) void agg_kernel(
        const unsigned* __restrict__ ekey, const unsigned* __restrict__ cnt,
        const float* __restrict__ h, unsigned* __restrict__ af) {
    __shared__ __align__(16) _Float16 Mlds[AGW][48 * PM];
    __shared__ __align__(16) _Float16 rT[AGW][16 * PM];
    __shared__ unsigned keyd[AGW][BCAP];
    __shared__ float degL[AGW][48];
    const int wave = threadIdx.x >> 6, lane = threadIdx.x & 63;
    const int n = blockIdx.x * AGW + wave;

    if (lane < 48) degL[wave][lane] = 0.f;
    {   // zero rT
        unsigned* rz = (unsigned*)&rT[wave][0];
        #pragma unroll
        for (int t = 0; t < 9; ++t) rz[lane + t * 64] = 0u;
    }
    const int deg = compact_keys(cnt, ekey, n, lane, keyd[wave]);

    f32x4 d0 = {0.f, 0.f, 0.f, 0.f};
    f32x4 d1 = {0.f, 0.f, 0.f, 0.f};
    f32x4 d2 = {0.f, 0.f, 0.f, 0.f};
    const f16x8 Z = {};

    for (int c0 = 0; c0 < deg; c0 += 64) {
        #pragma unroll
        for (int t = 0; t < 6; ++t) {
            int j = lane + t * 64;
            *(f16x8*)&Mlds[wave][(j >> 3) * PM + (j & 7) * 8] = Z;
        }
        const int degc = min(deg - c0, 64);

        if (lane < degc) {
            unsigned key = keyd[wave][c0 + lane];
            int r = key >> 16;
            Mlds[wave][r * PM + lane] = (_Float16)1.f;
            atomicAdd(&degL[wave][r], 1.f);
        }

        {   // gather h rows -> rT (transposed, f16)
            const int g = lane >> 2, q = (lane & 3) * 4;
            for (int i = 0; i < degc; i += 16) {
                int kl = min(i + g, degc - 1);
                unsigned key = keyd[wave][c0 + kl];
                float4 v = *(const float4*)(h + (key & 0xFFFF) * NHID + q);
                rT[wave][(q + 0) * PM + kl] = (_Float16)v.x;
                rT[wave][(q + 1) * PM + kl] = (_Float16)v.y;
                rT[wave][(q + 2) * PM + kl] = (_Float16)v.z;
                rT[wave][(q + 3) * PM + kl] = (_Float16)v.w;
            }
        }

        const int nkt = (degc > 32) ? 2 : 1;
        for (int kt = 0; kt < nkt; ++kt) {
            const int ko = kt * 32 + (lane >> 4) * 8;
            f16x8 b  = *(const f16x8*)&rT[wave][(lane & 15) * PM + ko];
            f16x8 a0 = *(const f16x8*)&Mlds[wave][((lane & 15)) * PM + ko];
            f16x8 a1 = *(const f16x8*)&Mlds[wave][(16 + (lane & 15)) * PM + ko];
            f16x8 a2 = *(const f16x8*)&Mlds[wave][(32 + (lane & 15)) * PM + ko];
            d0 = __builtin_amdgcn_mfma_f32_16x16x32_f16(a0, b, d0, 0, 0, 0);
            d1 = __builtin_amdgcn_mfma_f32_16x16x32_f16(a1, b, d1, 0, 0, 0);
            d2 = __builtin_amdgcn_mfma_f32_16x16x32_f16(a2, b, d2, 0, 0, 0);
        }
    }

    _Float16* arow = (_Float16*)af + (size_t)n * KPAD;
    const int hh = lane & 15, rg = lane >> 4;
    #pragma unroll
    for (int mt = 0; mt < 3; ++mt) {
        f32x4 dv = (mt == 0) ? d0 : (mt == 1) ? d1 : d2;
        #pragma unroll
        for (int c = 0; c < 4; ++c) {
            int r = mt * 16 + rg * 4 + c;
            if (r <= RR) {
                float val = 0.f;
                if (r < RR) {
                    float dgc = degL[wave][r];
                    val = (dgc != 0.f) ? dv[c] / dgc : 0.f;
                }
                arow[r * 16 + hh] = (_Float16)val;
            }
        }
    }
}

// Pre-pack W2 (fp32) per-lane contiguous: W2pk[(kb*64+lane)*8 + j] = W2[kb*8+j][lane]
__global__ void pack_kernel(const float* __restrict__ W2, float* __restrict__ W2pk) {
    int idx = blockIdx.x * blockDim.x + threadIdx.x;
    if (idx >= KB * 64 * 8) return;
    int j = idx & 7, lane = (idx >> 3) & 63, kb = idx >> 9;
    int k = kb * 8 + j;
    W2pk[idx] = (k < RH && lane < NCLASS) ? W2[k * NCLASS + lane] : 0.f;
}

__device__ __forceinline__ void hacc(float& acc, unsigned u, float w0, float w1) {
    union { unsigned v; _Float16 x[2]; } t; t.v = u;
    acc += (float)t.x[0] * w0 + (float)t.x[1] * w1;
}

// GEMM + log-softmax: wave = 8 nodes, lane = class. af rows (f16) via
// wave-uniform loads; W2pk via per-lane contiguous float4 pairs. No LDS.
__global__ __launch_bounds__(512) void gemm_kernel(
        const unsigned* __restrict__ af, const float* __restrict__ W2pk,
        const float* __restrict__ b2, float* __restrict__ out) {
    const int tid = threadIdx.x;
    const int wv = __builtin_amdgcn_readfirstlane(tid >> 6);
    const int lane = tid & 63;
    const int nbase = blockIdx.x * 64 + wv * 8;

    const uint4* a0 = (const uint4*)(af + (size_t)(nbase + 0) * KU32);
    const uint4* a1 = (const uint4*)(af + (size_t)(nbase + 1) * KU32);
    const uint4* a2 = (const uint4*)(af + (size_t)(nbase + 2) * KU32);
    const uint4* a3 = (const uint4*)(af + (size_t)(nbase + 3) * KU32);
    const uint4* a4 = (const uint4*)(af + (size_t)(nbase + 4) * KU32);
    const uint4* a5 = (const uint4*)(af + (size_t)(nbase + 5) * KU32);
    const uint4* a6 = (const uint4*)(af + (size_t)(nbase + 6) * KU32);
    const uint4* a7 = (const uint4*)(af + (size_t)(nbase + 7) * KU32);

    float acc[8];
    #pragma unroll
    for (int q = 0; q < 8; ++q) acc[q] = 0.f;

    const float* wbase = W2pk + (size_t)lane * 8;
    for (int kb = 0; kb < KB; ++kb) {
        float4 wA = *(const float4*)(wbase + (size_t)kb * 512);
        float4 wB = *(const float4*)(wbase + (size_t)kb * 512 + 4);
        uint4 a[8];
        a[0] = a0[kb]; a[1] = a1[kb]; a[2] = a2[kb]; a[3] = a3[kb];
        a[4] = a4[kb]; a[5] = a5[kb]; a[6] = a6[kb]; a[7] = a7[kb];
        #pragma unroll
        for (int q = 0; q < 8; ++q) {
            hacc(acc[q], a[q].x, wA.x, wA.y);
            hacc(acc[q], a[q].y, wA.z, wA.w);
            hacc(acc[q], a[q].z, wB.x, wB.y);
            hacc(acc[q], a[q].w, wB.z, wB.w);
        }
    }

    const float bias = (lane < NCLASS) ? b2[lane] : 0.f;
    #pragma unroll
    for (int q = 0; q < 8; ++q) {
        const int n = nbase + q;
        if (n < NN) {
            float x = (lane < NCLASS) ? acc[q] + bias : -INFINITY;
            float m = x;
            #pragma unroll
            for (int off = 32; off; off >>= 1) m = fmaxf(m, __shfl_xor(m, off));
            float ex = (lane < NCLASS) ? expf(x - m) : 0.f;
            float ss = ex;
            #pragma unroll
            for (int off = 32; off; off >>= 1) ss += __shfl_xor(ss, off);
            float ls = logf(ss) + m;
            if (lane < NCLASS) out[n * NCLASS + lane] = x - ls;
        }
    }
}

extern "C" void kernel_launch(void* const* d_in, const int* in_sizes, int n_in,
                              void* d_out, int out_size, void* d_ws, size_t ws_size,
                              hipStream_t stream) {
    const int*   src = (const int*)d_in[0];
    const int*   rel = (const int*)d_in[1];
    const int*   dst = (const int*)d_in[2];
    const float* W1  = (const float*)d_in[3];
    const float* b1  = (const float*)d_in[4];
    const float* W2  = (const float*)d_in[5];
    const float* b2  = (const float*)d_in[6];
    float* out = (float*)d_out;

    unsigned* cnt  = (unsigned*)d_ws;                        // NN*NSEG (1.6 MB)
    unsigned* ekey = cnt + (size_t)NN * NSEG;                // NN*BCAP (25.6 MB)
    float*    h    = (float*)(ekey + (size_t)NN * BCAP);     // NN*NHID (3.2 MB)
    unsigned* af   = (unsigned*)(h + (size_t)NN * NHID);     // NROWS*KU32 (67.3 MB)
    float*    W2pk = (float*)(af + (size_t)NROWS * KU32);    // KB*512 (172 KB)

    const int blk = 256;
    init_kernel<<<(NN + blk - 1) / blk, blk, 0, stream>>>(cnt, ekey);
    scatter_kernel<<<(EB + blk - 1) / blk, blk, 0, stream>>>(src, rel, dst, cnt, ekey);
    pack_kernel<<<(KB * 512 + blk - 1) / blk, blk, 0, stream>>>(W2, W2pk);
    layer1_kernel<<<NN / AGW, blk, 0, stream>>>(ekey, cnt, W1, b1, h);
    agg_kernel<<<NN / AGW, blk, 0, stream>>>(ekey, cnt, h, af);
    gemm_kernel<<<(NN + 63) / 64, 512, 0, stream>>>(af, W2pk, b2, out);
}

// Round 13
// 408.823 us; speedup vs baseline: 3.1819x; 1.3061x over previous
//
#include <hip/hip_runtime.h>

#define NN     50000
#define NRELB  20
#define RR     (2*NRELB + 1)      // 41
#define NHID   16
#define NCLASS 50
#define EB     1600000
#define RH     (RR * NHID)        // 656
#define STRIDE 128                // per-node bucket capacity (max deg+1 ~ 105)
#define KPAD   672                // 656 padded to 42*16
#define KU32   (KPAD/2)           // 336 u32 (f16 pairs) per af row
#define KB     (KPAD/8)           // 84 k-blocks of 8
#define NROWS  50048              // 782*64 af rows (padded)
#define PM     72                 // padded k-stride (elems) for M and rT
#define AGW    4                  // waves (= nodes) per block (layer1 + agg)

#define NBIN   391                // node-range bins (128 nodes each, s>>7)
#define BINCAP 12288              // records per bin (mean 8184, max ~8600)
#define TILE   2048               // edges per scat1 block
#define EPT    8                  // edges per thread in scat1

using f16x8 = __attribute__((ext_vector_type(8))) _Float16;
using f32x4 = __attribute__((ext_vector_type(4))) float;

// Pass 1: bin base edges (fwd+inv records) by target-node range.
// Block-aggregated reservation: ~0.1 global atomics/record; appends are
// contiguous runs per bin -> full-line write combining in LLC.
__global__ __launch_bounds__(256) void scat1_kernel(
        const int* __restrict__ src, const int* __restrict__ rel,
        const int* __restrict__ dst,
        unsigned* __restrict__ gBinCur, unsigned* __restrict__ gRecs) {
    __shared__ unsigned binCnt[NBIN], binOff[NBIN], binBase[NBIN];
    const int tid = threadIdx.x;
    for (int i = tid; i < NBIN; i += 256) { binCnt[i] = 0u; binOff[i] = 0u; }
    __syncthreads();

    const int e0 = blockIdx.x * TILE;
    unsigned rec[2 * EPT], bn[2 * EPT];
    bool val[EPT];
    #pragma unroll
    for (int k = 0; k < EPT; ++k) {
        int e = e0 + k * 256 + tid;
        val[k] = (e < EB);
        unsigned s = 0, r = 0, o = 0;
        if (val[k]) { s = (unsigned)src[e]; r = (unsigned)rel[e]; o = (unsigned)dst[e]; }
        bn[2*k]    = s >> 7;                                            // fwd -> bucket s
        rec[2*k]   = ((s & 127u) << 22) | (r << 16) | o;
        bn[2*k+1]  = o >> 7;                                            // inv -> bucket o
        rec[2*k+1] = ((o & 127u) << 22) | ((r + NRELB) << 16) | s;
    }
    #pragma unroll
    for (int k = 0; k < EPT; ++k)
        if (val[k]) {
            atomicAdd(&binCnt[bn[2*k]], 1u);
            atomicAdd(&binCnt[bn[2*k+1]], 1u);
        }
    __syncthreads();
    for (int b = tid; b < NBIN; b += 256) {
        unsigned c = binCnt[b];
        if (c) binBase[b] = atomicAdd(&gBinCur[b], c);
    }
    __syncthreads();
    #pragma unroll
    for (int k = 0; k < 2 * EPT; ++k)
        if (val[k >> 1]) {
            unsigned b = bn[k];
            unsigned pos = binBase[b] + atomicAdd(&binOff[b], 1u);
            if (pos < BINCAP) gRecs[(size_t)b * BINCAP + pos] = rec[k];
        }
}

// Pass 2: one block per bin (128 nodes). Stream records, LDS slot counters,
// dense per-node bucket writes into one 64KB region (L2-resident -> full-line
// writebacks). Self-loop at slot 0. Zero global atomics.
__global__ __launch_bounds__(256) void scat2_kernel(
        const unsigned* __restrict__ gBinCur, const unsigned* __restrict__ gRecs,
        unsigned* __restrict__ cnt, unsigned* __restrict__ ekey) {
    __shared__ unsigned off[128];
    const int b = blockIdx.x, tid = threadIdx.x;
    if (tid < 128) off[tid] = 1u;        // slot 0 reserved for self-loop
    __syncthreads();
    const unsigned M = min(gBinCur[b], (unsigned)BINCAP);
    const unsigned* recs = gRecs + (size_t)b * BINCAP;
    for (unsigned i0 = 0; i0 < M; i0 += 1024) {           // 4-way MLP
        unsigned i;
        unsigned r0 = 0, r1 = 0, r2 = 0, r3 = 0;
        bool v0, v1, v2, v3;
        i = i0 + tid;        v0 = i < M; if (v0) r0 = recs[i];
        i = i0 + 256 + tid;  v1 = i < M; if (v1) r1 = recs[i];
        i = i0 + 512 + tid;  v2 = i < M; if (v2) r2 = recs[i];
        i = i0 + 768 + tid;  v3 = i < M; if (v3) r3 = recs[i];
        if (v0) {
            unsigned sl = r0 >> 22, slot = atomicAdd(&off[sl], 1u), n = b * 128u + sl;
            if (slot < STRIDE && n < NN) ekey[(size_t)n * STRIDE + slot] = r0 & 0x3FFFFFu;
        }
        if (v1) {
            unsigned sl = r1 >> 22, slot = atomicAdd(&off[sl], 1u), n = b * 128u + sl;
            if (slot < STRIDE && n < NN) ekey[(size_t)n * STRIDE + slot] = r1 & 0x3FFFFFu;
        }
        if (v2) {
            unsigned sl = r2 >> 22, slot = atomicAdd(&off[sl], 1u), n = b * 128u + sl;
            if (slot < STRIDE && n < NN) ekey[(size_t)n * STRIDE + slot] = r2 & 0x3FFFFFu;
        }
        if (v3) {
            unsigned sl = r3 >> 22, slot = atomicAdd(&off[sl], 1u), n = b * 128u + sl;
            if (slot < STRIDE && n < NN) ekey[(size_t)n * STRIDE + slot] = r3 & 0x3FFFFFu;
        }
    }
    __syncthreads();
    if (tid < 128) {
        unsigned n = b * 128u + (unsigned)tid;
        if (n < NN) {
            ekey[(size_t)n * STRIDE] = ((unsigned)(2 * NRELB) << 16) | n;
            cnt[n] = min(off[tid], (unsigned)STRIDE);
        }
    }
}

// Layer 1 via per-node mini-MFMA: acc[r][h] = M[48][64] @ W1rows[64][16].
// Epilogue: scale rows by 1/deg_r, SUM over r, +bias, ReLU -> h[n][16] (f32).
__global__ __launch_bounds__(256) void layer1_kernel(
        const unsigned* __restrict__ ekey, const unsigned* __restrict__ cnt,
        const float* __restrict__ W1, const float* __restrict__ b1,
        float* __restrict__ h) {
    __shared__ __align__(16) _Float16 Mlds[AGW][48 * PM];
    __shared__ __align__(16) _Float16 rT[AGW][16 * PM];
    __shared__ float degL[AGW][48];
    const int wave = threadIdx.x >> 6, lane = threadIdx.x & 63;
    const int n = blockIdx.x * AGW + wave;
    const unsigned* ek = ekey + (size_t)n * STRIDE;
    const int deg = cnt[n];

    if (lane < 48) degL[wave][lane] = 0.f;
    {   // zero rT (16*PM f16 = 576 u32), wave-private
        unsigned* rz = (unsigned*)&rT[wave][0];
        #pragma unroll
        for (int t = 0; t < 9; ++t) rz[lane + t * 64] = 0u;
    }

    f32x4 d0 = {0.f, 0.f, 0.f, 0.f};
    f32x4 d1 = {0.f, 0.f, 0.f, 0.f};
    f32x4 d2 = {0.f, 0.f, 0.f, 0.f};
    const f16x8 Z = {};

    for (int c0 = 0; c0 < deg; c0 += 64) {
        #pragma unroll
        for (int t = 0; t < 6; ++t) {
            int j = lane + t * 64;
            *(f16x8*)&Mlds[wave][(j >> 3) * PM + (j & 7) * 8] = Z;
        }
        const int degc = min(deg - c0, 64);

        if (lane < degc) {
            unsigned key = ek[c0 + lane];
            int r = key >> 16;
            Mlds[wave][r * PM + lane] = (_Float16)1.f;
            atomicAdd(&degL[wave][r], 1.f);
        }

        {   // gather W1 rows -> rT (transposed, f16)
            const int g = lane >> 2, q = (lane & 3) * 4;
            for (int i = 0; i < degc; i += 16) {
                int kl = min(i + g, degc - 1);
                unsigned key = ek[c0 + kl];
                int r = key >> 16, o = key & 0xFFFF;
                float4 v = *(const float4*)(W1 + ((size_t)(r * NN + o)) * NHID + q);
                rT[wave][(q + 0) * PM + kl] = (_Float16)v.x;
                rT[wave][(q + 1) * PM + kl] = (_Float16)v.y;
                rT[wave][(q + 2) * PM + kl] = (_Float16)v.z;
                rT[wave][(q + 3) * PM + kl] = (_Float16)v.w;
            }
        }

        const int nkt = (degc > 32) ? 2 : 1;
        for (int kt = 0; kt < nkt; ++kt) {
            const int ko = kt * 32 + (lane >> 4) * 8;
            f16x8 b  = *(const f16x8*)&rT[wave][(lane & 15) * PM + ko];
            f16x8 a0 = *(const f16x8*)&Mlds[wave][((lane & 15)) * PM + ko];
            f16x8 a1 = *(const f16x8*)&Mlds[wave][(16 + (lane & 15)) * PM + ko];
            f16x8 a2 = *(const f16x8*)&Mlds[wave][(32 + (lane & 15)) * PM + ko];
            d0 = __builtin_amdgcn_mfma_f32_16x16x32_f16(a0, b, d0, 0, 0, 0);
            d1 = __builtin_amdgcn_mfma_f32_16x16x32_f16(a1, b, d1, 0, 0, 0);
            d2 = __builtin_amdgcn_mfma_f32_16x16x32_f16(a2, b, d2, 0, 0, 0);
        }
    }

    float partial = 0.f;
    const int rg = lane >> 4;
    #pragma unroll
    for (int mt = 0; mt < 3; ++mt) {
        f32x4 dv = (mt == 0) ? d0 : (mt == 1) ? d1 : d2;
        #pragma unroll
        for (int c = 0; c < 4; ++c) {
            int r = mt * 16 + rg * 4 + c;
            if (r < RR) {
                float dgc = degL[wave][r];
                partial += (dgc != 0.f) ? dv[c] / dgc : 0.f;
            }
        }
    }
    partial += __shfl_xor(partial, 16);
    partial += __shfl_xor(partial, 32);
    if (lane < NHID) h[n * NHID + lane] = fmaxf(partial + b1[lane], 0.f);
}

// Layer-2 aggregation via per-node mini-MFMA: af[r][h] = M[48][64] @ rows[64][16].
__global__ __launch_bounds__(256) void agg_kernel(
        const unsigned* __restrict__ ekey, const unsigned* __restrict__ cnt,
        const float* __restrict__ h, unsigned* __restrict__ af) {
    __shared__ __align__(16) _Float16 Mlds[AGW][48 * PM];
    __shared__ __align__(16) _Float16 rT[AGW][16 * PM];
    __shared__ float degL[AGW][48];
    const int wave = threadIdx.x >> 6, lane = threadIdx.x & 63;
    const int n = blockIdx.x * AGW + wave;
    const unsigned* ek = ekey + (size_t)n * STRIDE;
    const int deg = cnt[n];

    if (lane < 48) degL[wave][lane] = 0.f;
    {   // zero rT
        unsigned* rz = (unsigned*)&rT[wave][0];
        #pragma unroll
        for (int t = 0; t < 9; ++t) rz[lane + t * 64] = 0u;
    }

    f32x4 d0 = {0.f, 0.f, 0.f, 0.f};
    f32x4 d1 = {0.f, 0.f, 0.f, 0.f};
    f32x4 d2 = {0.f, 0.f, 0.f, 0.f};
    const f16x8 Z = {};

    for (int c0 = 0; c0 < deg; c0 += 64) {
        #pragma unroll
        for (int t = 0; t < 6; ++t) {
            int j = lane + t * 64;
            *(f16x8*)&Mlds[wave][(j >> 3) * PM + (j & 7) * 8] = Z;
        }
        const int degc = min(deg - c0, 64);

        if (lane < degc) {
            unsigned key = ek[c0 + lane];
            int r = key >> 16;
            Mlds[wave][r * PM + lane] = (_Float16)1.f;
            atomicAdd(&degL[wave][r], 1.f);
        }

        {   // gather h rows -> rT (transposed, f16)
            const int g = lane >> 2, q = (lane & 3) * 4;
            for (int i = 0; i < degc; i += 16) {
                int kl = min(i + g, degc - 1);
                unsigned key = ek[c0 + kl];
                float4 v = *(const float4*)(h + (key & 0xFFFF) * NHID + q);
                rT[wave][(q + 0) * PM + kl] = (_Float16)v.x;
                rT[wave][(q + 1) * PM + kl] = (_Float16)v.y;
                rT[wave][(q + 2) * PM + kl] = (_Float16)v.z;
                rT[wave][(q + 3) * PM + kl] = (_Float16)v.w;
            }
        }

        const int nkt = (degc > 32) ? 2 : 1;
        for (int kt = 0; kt < nkt; ++kt) {
            const int ko = kt * 32 + (lane >> 4) * 8;
            f16x8 b  = *(const f16x8*)&rT[wave][(lane & 15) * PM + ko];
            f16x8 a0 = *(const f16x8*)&Mlds[wave][((lane & 15)) * PM + ko];
            f16x8 a1 = *(const f16x8*)&Mlds[wave][(16 + (lane & 15)) * PM + ko];
            f16x8 a2 = *(const f16x8*)&Mlds[wave][(32 + (lane & 15)) * PM + ko];
            d0 = __builtin_amdgcn_mfma_f32_16x16x32_f16(a0, b, d0, 0, 0, 0);
            d1 = __builtin_amdgcn_mfma_f32_16x16x32_f16(a1, b, d1, 0, 0, 0);
            d2 = __builtin_amdgcn_mfma_f32_16x16x32_f16(a2, b, d2, 0, 0, 0);
        }
    }

    _Float16* arow = (_Float16*)af + (size_t)n * KPAD;
    const int hh = lane & 15, rg = lane >> 4;
    #pragma unroll
    for (int mt = 0; mt < 3; ++mt) {
        f32x4 dv = (mt == 0) ? d0 : (mt == 1) ? d1 : d2;
        #pragma unroll
        for (int c = 0; c < 4; ++c) {
            int r = mt * 16 + rg * 4 + c;
            if (r <= RR) {
                float val = 0.f;
                if (r < RR) {
                    float dgc = degL[wave][r];
                    val = (dgc != 0.f) ? dv[c] / dgc : 0.f;
                }
                arow[r * 16 + hh] = (_Float16)val;
            }
        }
    }
}

// Pre-pack W2 (fp32) per-lane contiguous: W2pk[(kb*64+lane)*8 + j] = W2[kb*8+j][lane]
__global__ void pack_kernel(const float* __restrict__ W2, float* __restrict__ W2pk) {
    int idx = blockIdx.x * blockDim.x + threadIdx.x;
    if (idx >= KB * 64 * 8) return;
    int j = idx & 7, lane = (idx >> 3) & 63, kb = idx >> 9;
    int k = kb * 8 + j;
    W2pk[idx] = (k < RH && lane < NCLASS) ? W2[k * NCLASS + lane] : 0.f;
}

__device__ __forceinline__ void hacc(float& acc, unsigned u, float w0, float w1) {
    union { unsigned v; _Float16 x[2]; } t; t.v = u;
    acc += (float)t.x[0] * w0 + (float)t.x[1] * w1;
}

// GEMM + log-softmax: wave = 8 nodes, lane = class. af rows (f16) via
// wave-uniform loads; W2pk via per-lane contiguous float4 pairs. No LDS.
__global__ __launch_bounds__(512) void gemm_kernel(
        const unsigned* __restrict__ af, const float* __restrict__ W2pk,
        const float* __restrict__ b2, float* __restrict__ out) {
    const int tid = threadIdx.x;
    const int wv = __builtin_amdgcn_readfirstlane(tid >> 6);
    const int lane = tid & 63;
    const int nbase = blockIdx.x * 64 + wv * 8;

    const uint4* a0 = (const uint4*)(af + (size_t)(nbase + 0) * KU32);
    const uint4* a1 = (const uint4*)(af + (size_t)(nbase + 1) * KU32);
    const uint4* a2 = (const uint4*)(af + (size_t)(nbase + 2) * KU32);
    const uint4* a3 = (const uint4*)(af + (size_t)(nbase + 3) * KU32);
    const uint4* a4 = (const uint4*)(af + (size_t)(nbase + 4) * KU32);
    const uint4* a5 = (const uint4*)(af + (size_t)(nbase + 5) * KU32);
    const uint4* a6 = (const uint4*)(af + (size_t)(nbase + 6) * KU32);
    const uint4* a7 = (const uint4*)(af + (size_t)(nbase + 7) * KU32);

    float acc[8];
    #pragma unroll
    for (int q = 0; q < 8; ++q) acc[q] = 0.f;

    const float* wbase = W2pk + (size_t)lane * 8;
    for (int kb = 0; kb < KB; ++kb) {
        float4 wA = *(const float4*)(wbase + (size_t)kb * 512);
        float4 wB = *(const float4*)(wbase + (size_t)kb * 512 + 4);
        uint4 a[8];
        a[0] = a0[kb]; a[1] = a1[kb]; a[2] = a2[kb]; a[3] = a3[kb];
        a[4] = a4[kb]; a[5] = a5[kb]; a[6] = a6[kb]; a[7] = a7[kb];
        #pragma unroll
        for (int q = 0; q < 8; ++q) {
            hacc(acc[q], a[q].x, wA.x, wA.y);
            hacc(acc[q], a[q].y, wA.z, wA.w);
            hacc(acc[q], a[q].z, wB.x, wB.y);
            hacc(acc[q], a[q].w, wB.z, wB.w);
        }
    }

    const float bias = (lane < NCLASS) ? b2[lane] : 0.f;
    #pragma unroll
    for (int q = 0; q < 8; ++q) {
        const int n = nbase + q;
        if (n < NN) {
            float x = (lane < NCLASS) ? acc[q] + bias : -INFINITY;
            float m = x;
            #pragma unroll
            for (int off = 32; off; off >>= 1) m = fmaxf(m, __shfl_xor(m, off));
            float ex = (lane < NCLASS) ? expf(x - m) : 0.f;
            float ss = ex;
            #pragma unroll
            for (int off = 32; off; off >>= 1) ss += __shfl_xor(ss, off);
            float ls = logf(ss) + m;
            if (lane < NCLASS) out[n * NCLASS + lane] = x - ls;
        }
    }
}

extern "C" void kernel_launch(void* const* d_in, const int* in_sizes, int n_in,
                              void* d_out, int out_size, void* d_ws, size_t ws_size,
                              hipStream_t stream) {
    const int*   src = (const int*)d_in[0];
    const int*   rel = (const int*)d_in[1];
    const int*   dst = (const int*)d_in[2];
    const float* W1  = (const float*)d_in[3];
    const float* b1  = (const float*)d_in[4];
    const float* W2  = (const float*)d_in[5];
    const float* b2  = (const float*)d_in[6];
    float* out = (float*)d_out;

    unsigned* cnt  = (unsigned*)d_ws;                        // NN
    unsigned* ekey = cnt + NN;                               // NN*STRIDE (25.6 MB)
    float*    h    = (float*)(ekey + (size_t)NN * STRIDE);   // NN*NHID (3.2 MB)
    unsigned* af   = (unsigned*)(h + (size_t)NN * NHID);     // NROWS*KU32 (67.3 MB)
    float*    W2pk = (float*)(af + (size_t)NROWS * KU32);    // KB*512 (172 KB)
    unsigned* gBinCur = (unsigned*)(W2pk + KB * 512);        // 512 u32 (2 KB)
    unsigned* gRecs   = af;          // alias af: 391*12288*4B = 19.2 MB << 67.3 MB;
                                     // consumed by scat2 before agg writes af.

    const int blk = 256;
    hipMemsetAsync(gBinCur, 0, 512 * sizeof(unsigned), stream);
    scat1_kernel<<<(EB + TILE - 1) / TILE, blk, 0, stream>>>(src, rel, dst, gBinCur, gRecs);
    scat2_kernel<<<NBIN, blk, 0, stream>>>(gBinCur, gRecs, cnt, ekey);
    pack_kernel<<<(KB * 512 + blk - 1) / blk, blk, 0, stream>>>(W2, W2pk);
    layer1_kernel<<<NN / AGW, blk, 0, stream>>>(ekey, cnt, W1, b1, h);
    agg_kernel<<<NN / AGW, blk, 0, stream>>>(ekey, cnt, h, af);
    gemm_kernel<<<(NN + 63) / 64, 512, 0, stream>>>(af, W2pk, b2, out);
}

// Round 14
// 268.913 us; speedup vs baseline: 4.8374x; 1.5203x over previous
//
#include <hip/hip_runtime.h>

#define NN     50000
#define NRELB  20
#define RR     (2*NRELB + 1)      // 41
#define NHID   16
#define NCLASS 50
#define EB     1600000
#define RH     (RR * NHID)        // 656
#define STRIDE 128                // per-node bucket capacity (max deg+1 ~ 105)
#define KPAD   672                // 656 padded to 21*32
#define KU32   (KPAD/2)           // 336 u32 (f16 pairs) per af row
#define NKB    21                 // K-blocks of 32 in the gemm
#define NCT    4                  // class tiles of 16 (64 >= 50)
#define NROWS  50048              // 782*64 af rows (padded)
#define PM     72                 // padded k-stride (elems) for M and rT
#define AGW    4                  // waves (= nodes) per block (layer1 + agg)

#define NBIN   391                // node-range bins (128 nodes each, s>>7)
#define BINCAP 12288              // records per bin (mean 8184, max ~8600)
#define TILE   2048               // edges per scat1 block
#define EPT    8                  // edges per thread in scat1

using f16x8 = __attribute__((ext_vector_type(8))) _Float16;
using f32x4 = __attribute__((ext_vector_type(4))) float;

// Pass 1: bin base edges (fwd+inv records) by target-node range.
__global__ __launch_bounds__(256) void scat1_kernel(
        const int* __restrict__ src, const int* __restrict__ rel,
        const int* __restrict__ dst,
        unsigned* __restrict__ gBinCur, unsigned* __restrict__ gRecs) {
    __shared__ unsigned binCnt[NBIN], binOff[NBIN], binBase[NBIN];
    const int tid = threadIdx.x;
    for (int i = tid; i < NBIN; i += 256) { binCnt[i] = 0u; binOff[i] = 0u; }
    __syncthreads();

    const int e0 = blockIdx.x * TILE;
    unsigned rec[2 * EPT], bn[2 * EPT];
    bool val[EPT];
    #pragma unroll
    for (int k = 0; k < EPT; ++k) {
        int e = e0 + k * 256 + tid;
        val[k] = (e < EB);
        unsigned s = 0, r = 0, o = 0;
        if (val[k]) { s = (unsigned)src[e]; r = (unsigned)rel[e]; o = (unsigned)dst[e]; }
        bn[2*k]    = s >> 7;
        rec[2*k]   = ((s & 127u) << 22) | (r << 16) | o;
        bn[2*k+1]  = o >> 7;
        rec[2*k+1] = ((o & 127u) << 22) | ((r + NRELB) << 16) | s;
    }
    #pragma unroll
    for (int k = 0; k < EPT; ++k)
        if (val[k]) {
            atomicAdd(&binCnt[bn[2*k]], 1u);
            atomicAdd(&binCnt[bn[2*k+1]], 1u);
        }
    __syncthreads();
    for (int b = tid; b < NBIN; b += 256) {
        unsigned c = binCnt[b];
        if (c) binBase[b] = atomicAdd(&gBinCur[b], c);
    }
    __syncthreads();
    #pragma unroll
    for (int k = 0; k < 2 * EPT; ++k)
        if (val[k >> 1]) {
            unsigned b = bn[k];
            unsigned pos = binBase[b] + atomicAdd(&binOff[b], 1u);
            if (pos < BINCAP) gRecs[(size_t)b * BINCAP + pos] = rec[k];
        }
}

// Pass 2: one block per bin (128 nodes). Dense bucket writes; zero global atomics.
__global__ __launch_bounds__(256) void scat2_kernel(
        const unsigned* __restrict__ gBinCur, const unsigned* __restrict__ gRecs,
        unsigned* __restrict__ cnt, unsigned* __restrict__ ekey) {
    __shared__ unsigned off[128];
    const int b = blockIdx.x, tid = threadIdx.x;
    if (tid < 128) off[tid] = 1u;        // slot 0 reserved for self-loop
    __syncthreads();
    const unsigned M = min(gBinCur[b], (unsigned)BINCAP);
    const unsigned* recs = gRecs + (size_t)b * BINCAP;
    for (unsigned i0 = 0; i0 < M; i0 += 1024) {
        unsigned i;
        unsigned r0 = 0, r1 = 0, r2 = 0, r3 = 0;
        bool v0, v1, v2, v3;
        i = i0 + tid;        v0 = i < M; if (v0) r0 = recs[i];
        i = i0 + 256 + tid;  v1 = i < M; if (v1) r1 = recs[i];
        i = i0 + 512 + tid;  v2 = i < M; if (v2) r2 = recs[i];
        i = i0 + 768 + tid;  v3 = i < M; if (v3) r3 = recs[i];
        if (v0) {
            unsigned sl = r0 >> 22, slot = atomicAdd(&off[sl], 1u), n = b * 128u + sl;
            if (slot < STRIDE && n < NN) ekey[(size_t)n * STRIDE + slot] = r0 & 0x3FFFFFu;
        }
        if (v1) {
            unsigned sl = r1 >> 22, slot = atomicAdd(&off[sl], 1u), n = b * 128u + sl;
            if (slot < STRIDE && n < NN) ekey[(size_t)n * STRIDE + slot] = r1 & 0x3FFFFFu;
        }
        if (v2) {
            unsigned sl = r2 >> 22, slot = atomicAdd(&off[sl], 1u), n = b * 128u + sl;
            if (slot < STRIDE && n < NN) ekey[(size_t)n * STRIDE + slot] = r2 & 0x3FFFFFu;
        }
        if (v3) {
            unsigned sl = r3 >> 22, slot = atomicAdd(&off[sl], 1u), n = b * 128u + sl;
            if (slot < STRIDE && n < NN) ekey[(size_t)n * STRIDE + slot] = r3 & 0x3FFFFFu;
        }
    }
    __syncthreads();
    if (tid < 128) {
        unsigned n = b * 128u + (unsigned)tid;
        if (n < NN) {
            ekey[(size_t)n * STRIDE] = ((unsigned)(2 * NRELB) << 16) | n;
            cnt[n] = min(off[tid], (unsigned)STRIDE);
        }
    }
}

// Layer 1 via per-node mini-MFMA: acc[r][h] = M[48][64] @ W1rows[64][16].
__global__ __launch_bounds__(256) void layer1_kernel(
        const unsigned* __restrict__ ekey, const unsigned* __restrict__ cnt,
        const float* __restrict__ W1, const float* __restrict__ b1,
        float* __restrict__ h) {
    __shared__ __align__(16) _Float16 Mlds[AGW][48 * PM];
    __shared__ __align__(16) _Float16 rT[AGW][16 * PM];
    __shared__ float degL[AGW][48];
    const int wave = threadIdx.x >> 6, lane = threadIdx.x & 63;
    const int n = blockIdx.x * AGW + wave;
    const unsigned* ek = ekey + (size_t)n * STRIDE;
    const int deg = cnt[n];

    if (lane < 48) degL[wave][lane] = 0.f;
    {
        unsigned* rz = (unsigned*)&rT[wave][0];
        #pragma unroll
        for (int t = 0; t < 9; ++t) rz[lane + t * 64] = 0u;
    }

    f32x4 d0 = {0.f, 0.f, 0.f, 0.f};
    f32x4 d1 = {0.f, 0.f, 0.f, 0.f};
    f32x4 d2 = {0.f, 0.f, 0.f, 0.f};
    const f16x8 Z = {};

    for (int c0 = 0; c0 < deg; c0 += 64) {
        #pragma unroll
        for (int t = 0; t < 6; ++t) {
            int j = lane + t * 64;
            *(f16x8*)&Mlds[wave][(j >> 3) * PM + (j & 7) * 8] = Z;
        }
        const int degc = min(deg - c0, 64);

        if (lane < degc) {
            unsigned key = ek[c0 + lane];
            int r = key >> 16;
            Mlds[wave][r * PM + lane] = (_Float16)1.f;
            atomicAdd(&degL[wave][r], 1.f);
        }

        {
            const int g = lane >> 2, q = (lane & 3) * 4;
            for (int i = 0; i < degc; i += 16) {
                int kl = min(i + g, degc - 1);
                unsigned key = ek[c0 + kl];
                int r = key >> 16, o = key & 0xFFFF;
                float4 v = *(const float4*)(W1 + ((size_t)(r * NN + o)) * NHID + q);
                rT[wave][(q + 0) * PM + kl] = (_Float16)v.x;
                rT[wave][(q + 1) * PM + kl] = (_Float16)v.y;
                rT[wave][(q + 2) * PM + kl] = (_Float16)v.z;
                rT[wave][(q + 3) * PM + kl] = (_Float16)v.w;
            }
        }

        const int nkt = (degc > 32) ? 2 : 1;
        for (int kt = 0; kt < nkt; ++kt) {
            const int ko = kt * 32 + (lane >> 4) * 8;
            f16x8 b  = *(const f16x8*)&rT[wave][(lane & 15) * PM + ko];
            f16x8 a0 = *(const f16x8*)&Mlds[wave][((lane & 15)) * PM + ko];
            f16x8 a1 = *(const f16x8*)&Mlds[wave][(16 + (lane & 15)) * PM + ko];
            f16x8 a2 = *(const f16x8*)&Mlds[wave][(32 + (lane & 15)) * PM + ko];
            d0 = __builtin_amdgcn_mfma_f32_16x16x32_f16(a0, b, d0, 0, 0, 0);
            d1 = __builtin_amdgcn_mfma_f32_16x16x32_f16(a1, b, d1, 0, 0, 0);
            d2 = __builtin_amdgcn_mfma_f32_16x16x32_f16(a2, b, d2, 0, 0, 0);
        }
    }

    float partial = 0.f;
    const int rg = lane >> 4;
    #pragma unroll
    for (int mt = 0; mt < 3; ++mt) {
        f32x4 dv = (mt == 0) ? d0 : (mt == 1) ? d1 : d2;
        #pragma unroll
        for (int c = 0; c < 4; ++c) {
            int r = mt * 16 + rg * 4 + c;
            if (r < RR) {
                float dgc = degL[wave][r];
                partial += (dgc != 0.f) ? dv[c] / dgc : 0.f;
            }
        }
    }
    partial += __shfl_xor(partial, 16);
    partial += __shfl_xor(partial, 32);
    if (lane < NHID) h[n * NHID + lane] = fmaxf(partial + b1[lane], 0.f);
}

// Layer-2 aggregation via per-node mini-MFMA: af[r][h] = M[48][64] @ rows[64][16].
__global__ __launch_bounds__(256) void agg_kernel(
        const unsigned* __restrict__ ekey, const unsigned* __restrict__ cnt,
        const float* __restrict__ h, unsigned* __restrict__ af) {
    __shared__ __align__(16) _Float16 Mlds[AGW][48 * PM];
    __shared__ __align__(16) _Float16 rT[AGW][16 * PM];
    __shared__ float degL[AGW][48];
    const int wave = threadIdx.x >> 6, lane = threadIdx.x & 63;
    const int n = blockIdx.x * AGW + wave;
    const unsigned* ek = ekey + (size_t)n * STRIDE;
    const int deg = cnt[n];

    if (lane < 48) degL[wave][lane] = 0.f;
    {
        unsigned* rz = (unsigned*)&rT[wave][0];
        #pragma unroll
        for (int t = 0; t < 9; ++t) rz[lane + t * 64] = 0u;
    }

    f32x4 d0 = {0.f, 0.f, 0.f, 0.f};
    f32x4 d1 = {0.f, 0.f, 0.f, 0.f};
    f32x4 d2 = {0.f, 0.f, 0.f, 0.f};
    const f16x8 Z = {};

    for (int c0 = 0; c0 < deg; c0 += 64) {
        #pragma unroll
        for (int t = 0; t < 6; ++t) {
            int j = lane + t * 64;
            *(f16x8*)&Mlds[wave][(j >> 3) * PM + (j & 7) * 8] = Z;
        }
        const int degc = min(deg - c0, 64);

        if (lane < degc) {
            unsigned key = ek[c0 + lane];
            int r = key >> 16;
            Mlds[wave][r * PM + lane] = (_Float16)1.f;
            atomicAdd(&degL[wave][r], 1.f);
        }

        {
            const int g = lane >> 2, q = (lane & 3) * 4;
            for (int i = 0; i < degc; i += 16) {
                int kl = min(i + g, degc - 1);
                unsigned key = ek[c0 + kl];
                float4 v = *(const float4*)(h + (key & 0xFFFF) * NHID + q);
                rT[wave][(q + 0) * PM + kl] = (_Float16)v.x;
                rT[wave][(q + 1) * PM + kl] = (_Float16)v.y;
                rT[wave][(q + 2) * PM + kl] = (_Float16)v.z;
                rT[wave][(q + 3) * PM + kl] = (_Float16)v.w;
            }
        }

        const int nkt = (degc > 32) ? 2 : 1;
        for (int kt = 0; kt < nkt; ++kt) {
            const int ko = kt * 32 + (lane >> 4) * 8;
            f16x8 b  = *(const f16x8*)&rT[wave][(lane & 15) * PM + ko];
            f16x8 a0 = *(const f16x8*)&Mlds[wave][((lane & 15)) * PM + ko];
            f16x8 a1 = *(const f16x8*)&Mlds[wave][(16 + (lane & 15)) * PM + ko];
            f16x8 a2 = *(const f16x8*)&Mlds[wave][(32 + (lane & 15)) * PM + ko];
            d0 = __builtin_amdgcn_mfma_f32_16x16x32_f16(a0, b, d0, 0, 0, 0);
            d1 = __builtin_amdgcn_mfma_f32_16x16x32_f16(a1, b, d1, 0, 0, 0);
            d2 = __builtin_amdgcn_mfma_f32_16x16x32_f16(a2, b, d2, 0, 0, 0);
        }
    }

    _Float16* arow = (_Float16*)af + (size_t)n * KPAD;
    const int hh = lane & 15, rg = lane >> 4;
    #pragma unroll
    for (int mt = 0; mt < 3; ++mt) {
        f32x4 dv = (mt == 0) ? d0 : (mt == 1) ? d1 : d2;
        #pragma unroll
        for (int c = 0; c < 4; ++c) {
            int r = mt * 16 + rg * 4 + c;
            if (r <= RR) {
                float val = 0.f;
                if (r < RR) {
                    float dgc = degL[wave][r];
                    val = (dgc != 0.f) ? dv[c] / dgc : 0.f;
                }
                arow[r * 16 + hh] = (_Float16)val;
            }
        }
    }
}

// Pre-pack W2 -> f16 B-fragments for mfma_f32_16x16x32_f16:
// W2f[(((ct*NKB)+kb)*64 + lane)*8 + j] = W2[kb*32+(lane>>4)*8+j][ct*16+(lane&15)]
__global__ void pack_kernel(const float* __restrict__ W2, _Float16* __restrict__ W2f) {
    int idx = blockIdx.x * blockDim.x + threadIdx.x;
    if (idx >= NCT * NKB * 64 * 8) return;
    int j = idx & 7, lane = (idx >> 3) & 63, t = idx >> 9;
    int kb = t % NKB, ct = t / NKB;
    int k = kb * 32 + (lane >> 4) * 8 + j;
    int c = ct * 16 + (lane & 15);
    W2f[idx] = (_Float16)((k < RH && c < NCLASS) ? W2[k * NCLASS + c] : 0.f);
}

// GEMM + log-softmax via MFMA: wave = 16-node x 64-class tile.
// A: af row-slices (layout matches A-fragment: m=lane&15, k=(lane>>4)*8+j).
// B: pre-packed W2f fragments (L2-resident). 84 MFMA/wave.
__global__ __launch_bounds__(256) void gemm_kernel(
        const _Float16* __restrict__ af, const _Float16* __restrict__ W2f,
        const float* __restrict__ b2, float* __restrict__ out) {
    __shared__ float lg[4][16][68];
    const int wave = threadIdx.x >> 6, lane = threadIdx.x & 63;
    const int n0 = (blockIdx.x * 4 + wave) * 16;
    const int l15 = lane & 15, g = lane >> 4;

    f32x4 acc0 = {0.f,0.f,0.f,0.f}, acc1 = {0.f,0.f,0.f,0.f};
    f32x4 acc2 = {0.f,0.f,0.f,0.f}, acc3 = {0.f,0.f,0.f,0.f};

    const _Float16* arow = af + (size_t)(n0 + l15) * KPAD + g * 8;
    const _Float16* wrow = W2f + (size_t)lane * 8;
    for (int kb = 0; kb < NKB; ++kb) {
        f16x8 a = *(const f16x8*)(arow + kb * 32);
        f16x8 b0 = *(const f16x8*)(wrow + (size_t)(0 * NKB + kb) * 512);
        f16x8 b1 = *(const f16x8*)(wrow + (size_t)(1 * NKB + kb) * 512);
        f16x8 b2f = *(const f16x8*)(wrow + (size_t)(2 * NKB + kb) * 512);
        f16x8 b3 = *(const f16x8*)(wrow + (size_t)(3 * NKB + kb) * 512);
        acc0 = __builtin_amdgcn_mfma_f32_16x16x32_f16(a, b0, acc0, 0, 0, 0);
        acc1 = __builtin_amdgcn_mfma_f32_16x16x32_f16(a, b1, acc1, 0, 0, 0);
        acc2 = __builtin_amdgcn_mfma_f32_16x16x32_f16(a, b2f, acc2, 0, 0, 0);
        acc3 = __builtin_amdgcn_mfma_f32_16x16x32_f16(a, b3, acc3, 0, 0, 0);
    }

    // stage logits tile to LDS: row=(g*4+reg) [node], col=ct*16+l15 [class]
    #pragma unroll
    for (int ct = 0; ct < 4; ++ct) {
        f32x4 av = (ct == 0) ? acc0 : (ct == 1) ? acc1 : (ct == 2) ? acc2 : acc3;
        int c = ct * 16 + l15;
        float bias = (c < NCLASS) ? b2[c] : 0.f;
        #pragma unroll
        for (int reg = 0; reg < 4; ++reg)
            lg[wave][g * 4 + reg][c] = av[reg] + bias;
    }
    __syncthreads();

    // per-row log-softmax (16 rows per wave)
    for (int r = 0; r < 16; ++r) {
        const int n = n0 + r;
        float x = (lane < NCLASS) ? lg[wave][r][lane] : -INFINITY;
        float m = x;
        #pragma unroll
        for (int off = 32; off; off >>= 1) m = fmaxf(m, __shfl_xor(m, off));
        float ex = (lane < NCLASS) ? expf(x - m) : 0.f;
        float ss = ex;
        #pragma unroll
        for (int off = 32; off; off >>= 1) ss += __shfl_xor(ss, off);
        float ls = logf(ss) + m;
        if (lane < NCLASS && n < NN) out[n * NCLASS + lane] = x - ls;
    }
}

extern "C" void kernel_launch(void* const* d_in, const int* in_sizes, int n_in,
                              void* d_out, int out_size, void* d_ws, size_t ws_size,
                              hipStream_t stream) {
    const int*   src = (const int*)d_in[0];
    const int*   rel = (const int*)d_in[1];
    const int*   dst = (const int*)d_in[2];
    const float* W1  = (const float*)d_in[3];
    const float* b1  = (const float*)d_in[4];
    const float* W2  = (const float*)d_in[5];
    const float* b2  = (const float*)d_in[6];
    float* out = (float*)d_out;

    unsigned* cnt  = (unsigned*)d_ws;                        // NN
    unsigned* ekey = cnt + NN;                               // NN*STRIDE (25.6 MB)
    float*    h    = (float*)(ekey + (size_t)NN * STRIDE);   // NN*NHID (3.2 MB)
    unsigned* af   = (unsigned*)(h + (size_t)NN * NHID);     // NROWS*KU32 (67.3 MB)
    _Float16* W2f  = (_Float16*)(af + (size_t)NROWS * KU32); // 4*21*512 f16 (86 KB)
    unsigned* gBinCur = (unsigned*)(W2f + NCT * NKB * 512);  // 512 u32
    unsigned* gRecs   = af;          // alias af (19.2 MB << 67.3 MB), consumed
                                     // by scat2 before agg writes af.

    const int blk = 256;
    hipMemsetAsync(gBinCur, 0, 512 * sizeof(unsigned), stream);
    scat1_kernel<<<(EB + TILE - 1) / TILE, blk, 0, stream>>>(src, rel, dst, gBinCur, gRecs);
    scat2_kernel<<<NBIN, blk, 0, stream>>>(gBinCur, gRecs, cnt, ekey);
    pack_kernel<<<(NCT * NKB * 512 + blk - 1) / blk, blk, 0, stream>>>(W2, W2f);
    layer1_kernel<<<NN / AGW, blk, 0, stream>>>(ekey, cnt, W1, b1, h);
    agg_kernel<<<NN / AGW, blk, 0, stream>>>(ekey, cnt, h, af);
    gemm_kernel<<<NROWS / 64, blk, 0, stream>>>((const _Float16*)af, W2f, b2, out);
}

// Round 15
// 231.816 us; speedup vs baseline: 5.6115x; 1.1600x over previous
//
#include <hip/hip_runtime.h>

#define NN     50000
#define NRELB  20
#define RR     (2*NRELB + 1)      // 41
#define NHID   16
#define NCLASS 50
#define EB     1600000
#define RH     (RR * NHID)        // 656
#define STRIDE 128                // per-node bucket capacity (max deg+1 ~ 105)
#define KPAD   672                // 656 padded to 21*32
#define KU32   (KPAD/2)           // 336 u32 (f16 pairs) per af row
#define NKB    21                 // K-blocks of 32 in the gemm
#define NCT    4                  // class tiles of 16 (64 >= 50)
#define NROWS  50048              // 782*64 af rows (padded)
#define PM     72                 // padded k-stride (elems) for rT
#define AGW    4                  // waves (= nodes) per block (layer1 + agg)

#define NBIN   391                // node-range bins (128 nodes each, s>>7)
#define BINCAP 12288              // records per bin (mean 8184, max ~8600)
#define TILE   2048               // edges per scat1 block
#define EPT    8                  // edges per thread in scat1

using f16x8 = __attribute__((ext_vector_type(8))) _Float16;
using f32x4 = __attribute__((ext_vector_type(4))) float;
using u16x8 = __attribute__((ext_vector_type(8))) unsigned short;

// Pass 1: bin base edges (fwd+inv records) by target-node range.
__global__ __launch_bounds__(256) void scat1_kernel(
        const int* __restrict__ src, const int* __restrict__ rel,
        const int* __restrict__ dst,
        unsigned* __restrict__ gBinCur, unsigned* __restrict__ gRecs) {
    __shared__ unsigned binCnt[NBIN], binOff[NBIN], binBase[NBIN];
    const int tid = threadIdx.x;
    for (int i = tid; i < NBIN; i += 256) { binCnt[i] = 0u; binOff[i] = 0u; }
    __syncthreads();

    const int e0 = blockIdx.x * TILE;
    unsigned rec[2 * EPT], bn[2 * EPT];
    bool val[EPT];
    #pragma unroll
    for (int k = 0; k < EPT; ++k) {
        int e = e0 + k * 256 + tid;
        val[k] = (e < EB);
        unsigned s = 0, r = 0, o = 0;
        if (val[k]) { s = (unsigned)src[e]; r = (unsigned)rel[e]; o = (unsigned)dst[e]; }
        bn[2*k]    = s >> 7;
        rec[2*k]   = ((s & 127u) << 22) | (r << 16) | o;
        bn[2*k+1]  = o >> 7;
        rec[2*k+1] = ((o & 127u) << 22) | ((r + NRELB) << 16) | s;
    }
    #pragma unroll
    for (int k = 0; k < EPT; ++k)
        if (val[k]) {
            atomicAdd(&binCnt[bn[2*k]], 1u);
            atomicAdd(&binCnt[bn[2*k+1]], 1u);
        }
    __syncthreads();
    for (int b = tid; b < NBIN; b += 256) {
        unsigned c = binCnt[b];
        if (c) binBase[b] = atomicAdd(&gBinCur[b], c);
    }
    __syncthreads();
    #pragma unroll
    for (int k = 0; k < 2 * EPT; ++k)
        if (val[k >> 1]) {
            unsigned b = bn[k];
            unsigned pos = binBase[b] + atomicAdd(&binOff[b], 1u);
            if (pos < BINCAP) gRecs[(size_t)b * BINCAP + pos] = rec[k];
        }
}

// Pass 2: one block per bin (128 nodes). Dense bucket writes; zero global atomics.
__global__ __launch_bounds__(256) void scat2_kernel(
        const unsigned* __restrict__ gBinCur, const unsigned* __restrict__ gRecs,
        unsigned* __restrict__ cnt, unsigned* __restrict__ ekey) {
    __shared__ unsigned off[128];
    const int b = blockIdx.x, tid = threadIdx.x;
    if (tid < 128) off[tid] = 1u;        // slot 0 reserved for self-loop
    __syncthreads();
    const unsigned M = min(gBinCur[b], (unsigned)BINCAP);
    const unsigned* recs = gRecs + (size_t)b * BINCAP;
    for (unsigned i0 = 0; i0 < M; i0 += 1024) {
        unsigned i;
        unsigned r0 = 0, r1 = 0, r2 = 0, r3 = 0;
        bool v0, v1, v2, v3;
        i = i0 + tid;        v0 = i < M; if (v0) r0 = recs[i];
        i = i0 + 256 + tid;  v1 = i < M; if (v1) r1 = recs[i];
        i = i0 + 512 + tid;  v2 = i < M; if (v2) r2 = recs[i];
        i = i0 + 768 + tid;  v3 = i < M; if (v3) r3 = recs[i];
        if (v0) {
            unsigned sl = r0 >> 22, slot = atomicAdd(&off[sl], 1u), n = b * 128u + sl;
            if (slot < STRIDE && n < NN) ekey[(size_t)n * STRIDE + slot] = r0 & 0x3FFFFFu;
        }
        if (v1) {
            unsigned sl = r1 >> 22, slot = atomicAdd(&off[sl], 1u), n = b * 128u + sl;
            if (slot < STRIDE && n < NN) ekey[(size_t)n * STRIDE + slot] = r1 & 0x3FFFFFu;
        }
        if (v2) {
            unsigned sl = r2 >> 22, slot = atomicAdd(&off[sl], 1u), n = b * 128u + sl;
            if (slot < STRIDE && n < NN) ekey[(size_t)n * STRIDE + slot] = r2 & 0x3FFFFFu;
        }
        if (v3) {
            unsigned sl = r3 >> 22, slot = atomicAdd(&off[sl], 1u), n = b * 128u + sl;
            if (slot < STRIDE && n < NN) ekey[(size_t)n * STRIDE + slot] = r3 & 0x3FFFFFu;
        }
    }
    __syncthreads();
    if (tid < 128) {
        unsigned n = b * 128u + (unsigned)tid;
        if (n < NN) {
            ekey[(size_t)n * STRIDE] = ((unsigned)(2 * NRELB) << 16) | n;
            cnt[n] = min(off[tid], (unsigned)STRIDE);
        }
    }
}

// Build the three A-fragments (rows m, m+16, m+32 of the indicator matrix)
// in registers from the chunk's rel values.
__device__ __forceinline__ void mk_afrags(u16x8 rv, int m,
                                          f16x8& a0, f16x8& a1, f16x8& a2) {
    #pragma unroll
    for (int j = 0; j < 8; ++j) {
        a0[j] = (_Float16)(rv[j] == (unsigned short)m);
        a1[j] = (_Float16)(rv[j] == (unsigned short)(m + 16));
        a2[j] = (_Float16)(rv[j] == (unsigned short)(m + 32));
    }
}

// Layer 1 via per-node mini-MFMA: acc[r][h] = M[48][64] @ W1rows[64][16],
// with A-fragments built in registers (no Mlds -> 3x less LDS, ~2x occupancy).
__global__ __launch_bounds__(256) void layer1_kernel(
        const unsigned* __restrict__ ekey, const unsigned* __restrict__ cnt,
        const float* __restrict__ W1, const float* __restrict__ b1,
        float* __restrict__ h) {
    __shared__ __align__(16) _Float16 rT[AGW][16 * PM];
    __shared__ __align__(16) unsigned short relc[AGW][64];
    __shared__ float degL[AGW][48];
    const int wave = threadIdx.x >> 6, lane = threadIdx.x & 63;
    const int n = blockIdx.x * AGW + wave;
    const unsigned* ek = ekey + (size_t)n * STRIDE;
    const int deg = cnt[n];
    const int m = lane & 15;

    if (lane < 48) degL[wave][lane] = 0.f;
    {   // zero rT (finite values required: A=0 masks values, not NaNs)
        unsigned* rz = (unsigned*)&rT[wave][0];
        #pragma unroll
        for (int t = 0; t < 9; ++t) rz[lane + t * 64] = 0u;
    }

    f32x4 d0 = {0.f, 0.f, 0.f, 0.f};
    f32x4 d1 = {0.f, 0.f, 0.f, 0.f};
    f32x4 d2 = {0.f, 0.f, 0.f, 0.f};

    for (int c0 = 0; c0 < deg; c0 += 64) {
        const int degc = min(deg - c0, 64);
        {   // stage rel values (63 = no-relation pad) + degree histogram
            int r = 63;
            if (lane < degc) r = (int)(ek[c0 + lane] >> 16);
            relc[wave][lane] = (unsigned short)r;
            if (lane < degc) atomicAdd(&degL[wave][r], 1.f);
        }
        {   // gather W1 rows -> rT (transposed, f16); clamped tails benign
            const int g = lane >> 2, q = (lane & 3) * 4;
            for (int i = 0; i < degc; i += 16) {
                int kl = min(i + g, degc - 1);
                unsigned key = ek[c0 + kl];
                int r = key >> 16, o = key & 0xFFFF;
                float4 v = *(const float4*)(W1 + ((size_t)(r * NN + o)) * NHID + q);
                rT[wave][(q + 0) * PM + kl] = (_Float16)v.x;
                rT[wave][(q + 1) * PM + kl] = (_Float16)v.y;
                rT[wave][(q + 2) * PM + kl] = (_Float16)v.z;
                rT[wave][(q + 3) * PM + kl] = (_Float16)v.w;
            }
        }
        const int nkt = (degc > 32) ? 2 : 1;
        for (int kt = 0; kt < nkt; ++kt) {
            const int ko = kt * 32 + (lane >> 4) * 8;
            f16x8 b = *(const f16x8*)&rT[wave][m * PM + ko];
            u16x8 rv = *(const u16x8*)&relc[wave][ko];
            f16x8 a0, a1, a2;
            mk_afrags(rv, m, a0, a1, a2);
            d0 = __builtin_amdgcn_mfma_f32_16x16x32_f16(a0, b, d0, 0, 0, 0);
            d1 = __builtin_amdgcn_mfma_f32_16x16x32_f16(a1, b, d1, 0, 0, 0);
            d2 = __builtin_amdgcn_mfma_f32_16x16x32_f16(a2, b, d2, 0, 0, 0);
        }
    }

    float partial = 0.f;
    const int rg = lane >> 4;
    #pragma unroll
    for (int mt = 0; mt < 3; ++mt) {
        f32x4 dv = (mt == 0) ? d0 : (mt == 1) ? d1 : d2;
        #pragma unroll
        for (int c = 0; c < 4; ++c) {
            int r = mt * 16 + rg * 4 + c;
            if (r < RR) {
                float dgc = degL[wave][r];
                partial += (dgc != 0.f) ? dv[c] / dgc : 0.f;
            }
        }
    }
    partial += __shfl_xor(partial, 16);
    partial += __shfl_xor(partial, 32);
    if (lane < NHID) h[n * NHID + lane] = fmaxf(partial + b1[lane], 0.f);
}

// Layer-2 aggregation via per-node mini-MFMA, register A-fragments.
__global__ __launch_bounds__(256) void agg_kernel(
        const unsigned* __restrict__ ekey, const unsigned* __restrict__ cnt,
        const float* __restrict__ h, unsigned* __restrict__ af) {
    __shared__ __align__(16) _Float16 rT[AGW][16 * PM];
    __shared__ __align__(16) unsigned short relc[AGW][64];
    __shared__ float degL[AGW][48];
    const int wave = threadIdx.x >> 6, lane = threadIdx.x & 63;
    const int n = blockIdx.x * AGW + wave;
    const unsigned* ek = ekey + (size_t)n * STRIDE;
    const int deg = cnt[n];
    const int m = lane & 15;

    if (lane < 48) degL[wave][lane] = 0.f;
    {
        unsigned* rz = (unsigned*)&rT[wave][0];
        #pragma unroll
        for (int t = 0; t < 9; ++t) rz[lane + t * 64] = 0u;
    }

    f32x4 d0 = {0.f, 0.f, 0.f, 0.f};
    f32x4 d1 = {0.f, 0.f, 0.f, 0.f};
    f32x4 d2 = {0.f, 0.f, 0.f, 0.f};

    for (int c0 = 0; c0 < deg; c0 += 64) {
        const int degc = min(deg - c0, 64);
        {
            int r = 63;
            if (lane < degc) r = (int)(ek[c0 + lane] >> 16);
            relc[wave][lane] = (unsigned short)r;
            if (lane < degc) atomicAdd(&degL[wave][r], 1.f);
        }
        {   // gather h rows -> rT (transposed, f16)
            const int g = lane >> 2, q = (lane & 3) * 4;
            for (int i = 0; i < degc; i += 16) {
                int kl = min(i + g, degc - 1);
                unsigned key = ek[c0 + kl];
                float4 v = *(const float4*)(h + (key & 0xFFFF) * NHID + q);
                rT[wave][(q + 0) * PM + kl] = (_Float16)v.x;
                rT[wave][(q + 1) * PM + kl] = (_Float16)v.y;
                rT[wave][(q + 2) * PM + kl] = (_Float16)v.z;
                rT[wave][(q + 3) * PM + kl] = (_Float16)v.w;
            }
        }
        const int nkt = (degc > 32) ? 2 : 1;
        for (int kt = 0; kt < nkt; ++kt) {
            const int ko = kt * 32 + (lane >> 4) * 8;
            f16x8 b = *(const f16x8*)&rT[wave][m * PM + ko];
            u16x8 rv = *(const u16x8*)&relc[wave][ko];
            f16x8 a0, a1, a2;
            mk_afrags(rv, m, a0, a1, a2);
            d0 = __builtin_amdgcn_mfma_f32_16x16x32_f16(a0, b, d0, 0, 0, 0);
            d1 = __builtin_amdgcn_mfma_f32_16x16x32_f16(a1, b, d1, 0, 0, 0);
            d2 = __builtin_amdgcn_mfma_f32_16x16x32_f16(a2, b, d2, 0, 0, 0);
        }
    }

    _Float16* arow = (_Float16*)af + (size_t)n * KPAD;
    const int hh = lane & 15, rg = lane >> 4;
    #pragma unroll
    for (int mt = 0; mt < 3; ++mt) {
        f32x4 dv = (mt == 0) ? d0 : (mt == 1) ? d1 : d2;
        #pragma unroll
        for (int c = 0; c < 4; ++c) {
            int r = mt * 16 + rg * 4 + c;
            if (r <= RR) {
                float val = 0.f;
                if (r < RR) {
                    float dgc = degL[wave][r];
                    val = (dgc != 0.f) ? dv[c] / dgc : 0.f;
                }
                arow[r * 16 + hh] = (_Float16)val;
            }
        }
    }
}

// Pre-pack W2 -> f16 B-fragments for mfma_f32_16x16x32_f16.
__global__ void pack_kernel(const float* __restrict__ W2, _Float16* __restrict__ W2f) {
    int idx = blockIdx.x * blockDim.x + threadIdx.x;
    if (idx >= NCT * NKB * 64 * 8) return;
    int j = idx & 7, lane = (idx >> 3) & 63, t = idx >> 9;
    int kb = t % NKB, ct = t / NKB;
    int k = kb * 32 + (lane >> 4) * 8 + j;
    int c = ct * 16 + (lane & 15);
    W2f[idx] = (_Float16)((k < RH && c < NCLASS) ? W2[k * NCLASS + c] : 0.f);
}

// GEMM + log-softmax via MFMA: wave = 16-node x 64-class tile.
__global__ __launch_bounds__(256) void gemm_kernel(
        const _Float16* __restrict__ af, const _Float16* __restrict__ W2f,
        const float* __restrict__ b2, float* __restrict__ out) {
    __shared__ float lg[4][16][68];
    const int wave = threadIdx.x >> 6, lane = threadIdx.x & 63;
    const int n0 = (blockIdx.x * 4 + wave) * 16;
    const int l15 = lane & 15, g = lane >> 4;

    f32x4 acc0 = {0.f,0.f,0.f,0.f}, acc1 = {0.f,0.f,0.f,0.f};
    f32x4 acc2 = {0.f,0.f,0.f,0.f}, acc3 = {0.f,0.f,0.f,0.f};

    const _Float16* arow = af + (size_t)(n0 + l15) * KPAD + g * 8;
    const _Float16* wrow = W2f + (size_t)lane * 8;
    for (int kb = 0; kb < NKB; ++kb) {
        f16x8 a = *(const f16x8*)(arow + kb * 32);
        f16x8 b0 = *(const f16x8*)(wrow + (size_t)(0 * NKB + kb) * 512);
        f16x8 b1 = *(const f16x8*)(wrow + (size_t)(1 * NKB + kb) * 512);
        f16x8 b2f = *(const f16x8*)(wrow + (size_t)(2 * NKB + kb) * 512);
        f16x8 b3 = *(const f16x8*)(wrow + (size_t)(3 * NKB + kb) * 512);
        acc0 = __builtin_amdgcn_mfma_f32_16x16x32_f16(a, b0, acc0, 0, 0, 0);
        acc1 = __builtin_amdgcn_mfma_f32_16x16x32_f16(a, b1, acc1, 0, 0, 0);
        acc2 = __builtin_amdgcn_mfma_f32_16x16x32_f16(a, b2f, acc2, 0, 0, 0);
        acc3 = __builtin_amdgcn_mfma_f32_16x16x32_f16(a, b3, acc3, 0, 0, 0);
    }

    #pragma unroll
    for (int ct = 0; ct < 4; ++ct) {
        f32x4 av = (ct == 0) ? acc0 : (ct == 1) ? acc1 : (ct == 2) ? acc2 : acc3;
        int c = ct * 16 + l15;
        float bias = (c < NCLASS) ? b2[c] : 0.f;
        #pragma unroll
        for (int reg = 0; reg < 4; ++reg)
            lg[wave][g * 4 + reg][c] = av[reg] + bias;
    }
    __syncthreads();

    for (int r = 0; r < 16; ++r) {
        const int n = n0 + r;
        float x = (lane < NCLASS) ? lg[wave][r][lane] : -INFINITY;
        float m = x;
        #pragma unroll
        for (int off = 32; off; off >>= 1) m = fmaxf(m, __shfl_xor(m, off));
        float ex = (lane < NCLASS) ? expf(x - m) : 0.f;
        float ss = ex;
        #pragma unroll
        for (int off = 32; off; off >>= 1) ss += __shfl_xor(ss, off);
        float ls = logf(ss) + m;
        if (lane < NCLASS && n < NN) out[n * NCLASS + lane] = x - ls;
    }
}

extern "C" void kernel_launch(void* const* d_in, const int* in_sizes, int n_in,
                              void* d_out, int out_size, void* d_ws, size_t ws_size,
                              hipStream_t stream) {
    const int*   src = (const int*)d_in[0];
    const int*   rel = (const int*)d_in[1];
    const int*   dst = (const int*)d_in[2];
    const float* W1  = (const float*)d_in[3];
    const float* b1  = (const float*)d_in[4];
    const float* W2  = (const float*)d_in[5];
    const float* b2  = (const float*)d_in[6];
    float* out = (float*)d_out;

    unsigned* cnt  = (unsigned*)d_ws;                        // NN
    unsigned* ekey = cnt + NN;                               // NN*STRIDE (25.6 MB)
    float*    h    = (float*)(ekey + (size_t)NN * STRIDE);   // NN*NHID (3.2 MB)
    unsigned* af   = (unsigned*)(h + (size_t)NN * NHID);     // NROWS*KU32 (67.3 MB)
    _Float16* W2f  = (_Float16*)(af + (size_t)NROWS * KU32); // 4*21*512 f16 (86 KB)
    unsigned* gBinCur = (unsigned*)(W2f + NCT * NKB * 512);  // 512 u32
    unsigned* gRecs   = af;          // alias af (19.2 MB << 67.3 MB), consumed
                                     // by scat2 before agg writes af.

    const int blk = 256;
    hipMemsetAsync(gBinCur, 0, 512 * sizeof(unsigned), stream);
    scat1_kernel<<<(EB + TILE - 1) / TILE, blk, 0, stream>>>(src, rel, dst, gBinCur, gRecs);
    scat2_kernel<<<NBIN, blk, 0, stream>>>(gBinCur, gRecs, cnt, ekey);
    pack_kernel<<<(NCT * NKB * 512 + blk - 1) / blk, blk, 0, stream>>>(W2, W2f);
    layer1_kernel<<<NN / AGW, blk, 0, stream>>>(ekey, cnt, W1, b1, h);
    agg_kernel<<<NN / AGW, blk, 0, stream>>>(ekey, cnt, h, af);
    gemm_kernel<<<NROWS / 64, blk, 0, stream>>>((const _Float16*)af, W2f, b2, out);
}